// Round 2
// baseline (579.718 us; speedup 1.0000x reference)
//
#include <hip/hip_runtime.h>
#include <stdint.h>
#include <stddef.h>

// Problem constants (B=4, L=1024, D=768, H=6, DH=128)
#define BB 4
#define LL 1024
#define DD 768
#define HH 6
#define DHH 128
#define EPS 1e-5f

// Output layout (fp32 elements, concatenated in return order):
//   co : (B,H,L,L) = 25165824
//   w  : (B,L,1)   = 4096
//   Vh : (B,H,L,DH)= 3145728
#define CO_ELEMS 25165824
#define W_ELEMS  4096

// ws layout (fp32 elements), ~12.9 MB.
#define OFF_Q2  0           // 24576
#define OFF_K2  24576       // 24576
#define OFF_WC  49152       // 24576  final col sums
#define OFF_SP  73728       // 6144   per-bh {sumS,sumS2} analytic moments
#define OFF_AC  79872       // 16     a1[0..7], c1[8..15]
#define OFF_SS  79888       // 192    BN2 (sum,sumsq) block partials
#define OFF_WP  81920       // 128*24*1024 = 3145728 col-sum half-strip partials
// total 3227648 floats = 12.91 MB

// Transposed truncated Q/K (fp32 with low mantissa zeroed) live in the co
// output region as scratch: QTf = co[0 .. 3145728), KTf = co[3145728 .. 6291456).
// Consumed by k_moments strictly before k_fused overwrites co (stream order).

typedef __attribute__((ext_vector_type(8))) short short8;
typedef __attribute__((ext_vector_type(4))) float f32x4;

// load 8 contiguous fp32, truncate to bf16 fragment
__device__ __forceinline__ short8 ld_bf8(const float* __restrict__ p) {
    const float4 a = *(const float4*)(p);
    const float4 b = *(const float4*)(p + 4);
    short8 r;
    r[0] = (short)(__float_as_uint(a.x) >> 16);
    r[1] = (short)(__float_as_uint(a.y) >> 16);
    r[2] = (short)(__float_as_uint(a.z) >> 16);
    r[3] = (short)(__float_as_uint(a.w) >> 16);
    r[4] = (short)(__float_as_uint(b.x) >> 16);
    r[5] = (short)(__float_as_uint(b.y) >> 16);
    r[6] = (short)(__float_as_uint(b.z) >> 16);
    r[7] = (short)(__float_as_uint(b.w) >> 16);
    return r;
}

// ------------------------------------------------- q2 / k2 (row sq-norms)
__global__ void k_rownorm(const float* __restrict__ Q,
                          const float* __restrict__ K,
                          float* __restrict__ ws) {
    int gid = blockIdx.x * 256 + threadIdx.x;       // 196608
    int sub = gid & 3;
    int rg  = gid >> 2;
    int which = (rg >= 24576);
    int rid = which ? rg - 24576 : rg;              // bh*1024 + i
    int bh = rid >> 10, i = rid & 1023;
    int b = bh / HH, h = bh - b * HH;
    const float* src = (which ? K : Q) + (size_t)(b * LL + i) * DD + h * DHH;
    float s = 0.f;
#pragma unroll
    for (int kk = 0; kk < 8; kk++) {
        float4 v = *(const float4*)(src + (sub + 4 * kk) * 4);
        s += v.x * v.x + v.y * v.y + v.z * v.z + v.w * v.w;
    }
    s += __shfl_xor(s, 1);
    s += __shfl_xor(s, 2);
    if (sub == 0) ws[(which ? OFF_K2 : OFF_Q2) + rid] = s;
}

// ------------------------------------------------- Vh output (exact copy)
__global__ void k_vh(const float* __restrict__ V, float* __restrict__ out) {
    int cid = blockIdx.x * 256 + threadIdx.x;       // 786432 float4 chunks
    if (cid >= 786432) return;
    int d4 = cid & 31;
    int rest = cid >> 5;
    int l = rest & 1023;
    int bh = rest >> 10;
    int b = bh / HH, h = bh - b * HH;
    f32x4 v = *(const f32x4*)(V + (size_t)(b * LL + l) * DD + h * DHH + d4 * 4);
    __builtin_nontemporal_store(v, (f32x4*)(out + (size_t)cid * 4));
}

// ---- transpose + truncate Q,K into QTf/KTf [which][bh][128][1024] fp32
__global__ __launch_bounds__(256) void k_tr(const float* __restrict__ Q,
                                            const float* __restrict__ K,
                                            float* __restrict__ QTf) {
    const int ib = blockIdx.x * 128;      // 8 i-blocks of 128
    const int bh = blockIdx.y;            // 24
    const int which = blockIdx.z;         // 0=Q, 1=K
    const int b = bh / HH, h = bh - b * HH;
    const float* src = (which ? K : Q) + (size_t)b * LL * DD + h * DHH;
    float* dst = QTf + ((size_t)which * 24 + bh) * 131072;
    const int t = threadIdx.x;
    __shared__ float tile[64][129];

    for (int half = 0; half < 2; half++) {
        const int i0w = t >> 5;            // 0..7
        const int d0 = (t & 31) * 4;
#pragma unroll
        for (int rep = 0; rep < 8; rep++) {
            const int i_loc = rep * 8 + i0w;
            float4 v = *(const float4*)(src + (size_t)(ib + half * 64 + i_loc) * DD + d0);
            tile[i_loc][d0 + 0] = __uint_as_float(__float_as_uint(v.x) & 0xffff0000u);
            tile[i_loc][d0 + 1] = __uint_as_float(__float_as_uint(v.y) & 0xffff0000u);
            tile[i_loc][d0 + 2] = __uint_as_float(__float_as_uint(v.z) & 0xffff0000u);
            tile[i_loc][d0 + 3] = __uint_as_float(__float_as_uint(v.w) & 0xffff0000u);
        }
        __syncthreads();
        const int i4 = (t & 15) * 4;       // 0..60
        const int dr = t >> 4;             // 0..15
#pragma unroll
        for (int rep = 0; rep < 8; rep++) {
            const int d_loc = rep * 16 + dr;
            f32x4 o;
            o[0] = tile[i4 + 0][d_loc];
            o[1] = tile[i4 + 1][d_loc];
            o[2] = tile[i4 + 2][d_loc];
            o[3] = tile[i4 + 3][d_loc];
            *(f32x4*)(dst + (size_t)d_loc * 1024 + ib + half * 64 + i4) = o;
        }
        __syncthreads();
    }
}

// ---- analytic BN1 moments per bh (no LxL pass!):
// sumS  = 2*dotA - 1024*(Sq2+Sk2)
// sumS2 = 4*<GQ,GK> + 1024*(Sq2sq+Sk2sq) + 2*Sq2*Sk2 - 4*(dotBq+dotBk)
// using the SAME truncated-bf16 values / MFMA as the recompute pass.
__global__ __launch_bounds__(256) void k_moments(
        const float* __restrict__ QTf,
        const float* __restrict__ q2, const float* __restrict__ k2,
        float* __restrict__ statsP) {
    const int bh = blockIdx.x;
    const int t = threadIdx.x, lane = t & 63, w = t >> 6;
    const int lm = lane & 15, quad = lane >> 4;
    __shared__ float sQ[128], sK[128], sQq2[128], sKk2[128];
    __shared__ float sred[4][4];
    __shared__ float gred[4];

    const float* QTb = QTf + (size_t)bh * 131072;
    const float* KTb = QTf + (size_t)(24 + bh) * 131072;
    const float* q2b = q2 + bh * 1024;
    const float* k2b = k2 + bh * 1024;

    // part 1: per-d sums  sQ[d]=sum_i tq, sQq2[d]=sum_i tq*q2  (K analog)
    {
        const int d = t & 127;
        const int which = t >> 7;
        const float* row = (which ? KTb : QTb) + (size_t)d * 1024;
        const float* sc  = which ? k2b : q2b;
        float s1 = 0.f, s2 = 0.f;
#pragma unroll 4
        for (int i = 0; i < 1024; i += 4) {
            f32x4 v = *(const f32x4*)(row + i);
            f32x4 u = *(const f32x4*)(sc + i);
            s1 += (v[0] + v[1]) + (v[2] + v[3]);
            s2 += v[0] * u[0] + v[1] * u[1] + v[2] * u[2] + v[3] * u[3];
        }
        if (which) { sK[d] = s1; sKk2[d] = s2; }
        else       { sQ[d] = s1; sQq2[d] = s2; }
    }
    // part 2: scalar sums of q2/k2 (and squares)
    {
        f32x4 qv = *(const f32x4*)(q2b + t * 4);
        f32x4 kv = *(const f32x4*)(k2b + t * 4);
        float p0 = qv[0] + qv[1] + qv[2] + qv[3];
        float p1 = qv[0]*qv[0] + qv[1]*qv[1] + qv[2]*qv[2] + qv[3]*qv[3];
        float p2 = kv[0] + kv[1] + kv[2] + kv[3];
        float p3 = kv[0]*kv[0] + kv[1]*kv[1] + kv[2]*kv[2] + kv[3]*kv[3];
#pragma unroll
        for (int off = 1; off < 64; off <<= 1) {
            p0 += __shfl_xor(p0, off); p1 += __shfl_xor(p1, off);
            p2 += __shfl_xor(p2, off); p3 += __shfl_xor(p3, off);
        }
        if (lane == 0) { sred[w][0] = p0; sred[w][1] = p1; sred[w][2] = p2; sred[w][3] = p3; }
    }
    __syncthreads();
    // part 3: <GQ,GK> via paired MFMA Gram tiles (upper-triangular, weight 2)
    float gg = 0.f;
    {
        int pi = 0;
        for (int dt = 0; dt < 8; dt++)
            for (int et = dt; et < 8; et++, pi++) {
                if ((pi & 3) != w) continue;
                const float* qa = QTb + (size_t)(dt * 16 + lm) * 1024 + quad * 8;
                const float* qb = QTb + (size_t)(et * 16 + lm) * 1024 + quad * 8;
                const float* ka = KTb + (size_t)(dt * 16 + lm) * 1024 + quad * 8;
                const float* kb = KTb + (size_t)(et * 16 + lm) * 1024 + quad * 8;
                f32x4 aq = (f32x4)(0.0f), ak = (f32x4)(0.0f);
                for (int kk = 0; kk < 32; kk++) {
                    aq = __builtin_amdgcn_mfma_f32_16x16x32_bf16(ld_bf8(qa + kk * 32), ld_bf8(qb + kk * 32), aq, 0, 0, 0);
                    ak = __builtin_amdgcn_mfma_f32_16x16x32_bf16(ld_bf8(ka + kk * 32), ld_bf8(kb + kk * 32), ak, 0, 0, 0);
                }
                float d4 = aq[0]*ak[0] + aq[1]*ak[1] + aq[2]*ak[2] + aq[3]*ak[3];
                gg += (dt == et) ? d4 : 2.0f * d4;
            }
#pragma unroll
        for (int off = 1; off < 64; off <<= 1) gg += __shfl_xor(gg, off);
        if (lane == 0) gred[w] = gg;
    }
    __syncthreads();
    // part 4: assemble
    if (t < 64) {
        float dA  = sQ[t] * sK[t] + sQ[t + 64] * sK[t + 64];
        float dBq = sQq2[t] * sK[t] + sQq2[t + 64] * sK[t + 64];
        float dBk = sQ[t] * sKk2[t] + sQ[t + 64] * sKk2[t + 64];
#pragma unroll
        for (int off = 1; off < 64; off <<= 1) {
            dA += __shfl_xor(dA, off); dBq += __shfl_xor(dBq, off); dBk += __shfl_xor(dBk, off);
        }
        if (t == 0) {
            float SQ2   = sred[0][0] + sred[1][0] + sred[2][0] + sred[3][0];
            float SQ2SQ = sred[0][1] + sred[1][1] + sred[2][1] + sred[3][1];
            float SK2   = sred[0][2] + sred[1][2] + sred[2][2] + sred[3][2];
            float SK2SQ = sred[0][3] + sred[1][3] + sred[2][3] + sred[3][3];
            float GG = gred[0] + gred[1] + gred[2] + gred[3];
            float sumS  = 2.f * dA - 1024.f * (SQ2 + SK2);
            float sumS2 = 4.f * GG + 1024.f * (SQ2SQ + SK2SQ) + 2.f * SQ2 * SK2 - 4.f * (dBq + dBk);
            statsP[bh * 2]     = sumS;
            statsP[bh * 2 + 1] = sumS2;
        }
    }
}

// --------------------------------------------- BN1 stats -> ac
__global__ void k_stats2(const float* __restrict__ statsP,
                         const float* __restrict__ g1, const float* __restrict__ b1,
                         float* __restrict__ ac) {
    const int t = threadIdx.x;
    if (t < HH) {
        float T1 = 0.f, T2 = 0.f;
#pragma unroll
        for (int b = 0; b < 4; b++) {
            T1 += statsP[(b * HH + t) * 2];
            T2 += statsP[(b * HH + t) * 2 + 1];
        }
        const float N = 4194304.f;                 // 4*1024*1024
        float m_ = T1 / N;
        float var = fmaxf(T2 / N - m_ * m_, 0.0f);
        float r = rsqrtf(var + EPS);
        float a = r * g1[t];
        ac[t] = a;
        ac[8 + t] = b1[t] - m_ * a;
    }
}

// ---- FUSED: recompute S via MFMA (verified R1 lane math), BN+mask+exp into
// a 16x1024 LDS strip, row-softmax, coalesced 1KB/wave NT stores, half-strip
// col-sum partials. grid.x = bh -> all strips of a bh on one XCD (24%8==0).
__global__ __launch_bounds__(512, 2) void k_fused(
        const float* __restrict__ Q, const float* __restrict__ Km,
        const float* __restrict__ q2, const float* __restrict__ k2,
        const float* __restrict__ ac, const unsigned char* __restrict__ bx,
        float* __restrict__ co, float* __restrict__ wcolP) {
    const int bh = blockIdx.x;            // 24
    const int strip = blockIdx.y;         // 64 strips of 16 rows
    const int b = bh / HH, h = bh - b * HH;
    const int t = threadIdx.x, lane = t & 63, w = t >> 6;   // 8 waves
    const int lm = lane & 15, quad = lane >> 4;
    const int i0 = strip * 16;
    const int jw = w * 128;               // wave's 128-col range

    __shared__ float e_lds[16][1028];     // padded: balanced LDS banks
    __shared__ float rowsum[16];
    if (t < 16) rowsum[t] = 0.f;
    __syncthreads();

    const float* Qb = Q + (size_t)b * LL * DD + h * DHH;
    const float* Kb = Km + (size_t)b * LL * DD + h * DHH;
    const float a1 = ac[h], c1 = ac[8 + h];
    const unsigned char* bxb = bx + b * LL;

    // Q fragments (B-operand): rows i0+lm, k-chunks by quad
    short8 qf[4];
#pragma unroll
    for (int kk = 0; kk < 4; kk++)
        qf[kk] = ld_bf8(Qb + (size_t)(i0 + lm) * DD + kk * 32 + quad * 8);

    const bool vi = (bxb[i0 + lm] == 0);
    const float q2v = q2[bh * 1024 + i0 + lm];

    float rsum = 0.f;
#pragma unroll
    for (int jt = 0; jt < 8; jt++) {
        const int jb = jw + jt * 16;
        short8 kf[4];
#pragma unroll
        for (int kk = 0; kk < 4; kk++)
            kf[kk] = ld_bf8(Kb + (size_t)(jb + lm) * DD + kk * 32 + quad * 8);
        f32x4 acc = (f32x4)(0.0f);
#pragma unroll
        for (int kk = 0; kk < 4; kk++)
            acc = __builtin_amdgcn_mfma_f32_16x16x32_bf16(kf[kk], qf[kk], acc, 0, 0, 0);
        // acc[r]: j = jb + quad*4 + r, i = i0 + lm
        const f32x4 k2v = *(const f32x4*)(k2 + bh * 1024 + jb + quad * 4);
        const uchar4 m4 = *(const uchar4*)(bxb + jb + quad * 4);
        f32x4 ev;
        ev[0] = (vi && m4.x == 0) ? __expf(fminf(a1 * (2.0f * acc[0] - q2v - k2v[0]) + c1, 60.0f)) : 1.0f;
        ev[1] = (vi && m4.y == 0) ? __expf(fminf(a1 * (2.0f * acc[1] - q2v - k2v[1]) + c1, 60.0f)) : 1.0f;
        ev[2] = (vi && m4.z == 0) ? __expf(fminf(a1 * (2.0f * acc[2] - q2v - k2v[2]) + c1, 60.0f)) : 1.0f;
        ev[3] = (vi && m4.w == 0) ? __expf(fminf(a1 * (2.0f * acc[3] - q2v - k2v[3]) + c1, 60.0f)) : 1.0f;
        *(f32x4*)&e_lds[lm][jb + quad * 4] = ev;
        rsum += (ev[0] + ev[1]) + (ev[2] + ev[3]);
    }
    // row-sum: reduce over quads, then across waves via 16 LDS atomics
    rsum += __shfl_xor(rsum, 16);
    rsum += __shfl_xor(rsum, 32);
    if (lane < 16) atomicAdd(&rowsum[lm], rsum);
    __syncthreads();

    // phase B: coalesced scaled stores + half-strip col sums
    const int cg = t & 255, rh = t >> 8;
    float* cob = co + ((size_t)bh << 20) + (size_t)(i0 + rh * 8) * 1024 + cg * 4;
    float* wp = wcolP + ((size_t)((strip * 2 + rh) * 24 + bh)) * 1024 + cg * 4;
    float cs0 = 0.f, cs1 = 0.f, cs2 = 0.f, cs3 = 0.f;
#pragma unroll
    for (int rr = 0; rr < 8; rr++) {
        const int r = rh * 8 + rr;
        const float inv = 1.0f / rowsum[r];
        f32x4 v = *(const f32x4*)&e_lds[r][cg * 4];
        v[0] *= inv; v[1] *= inv; v[2] *= inv; v[3] *= inv;
        __builtin_nontemporal_store(v, (f32x4*)(cob + (size_t)rr * 1024));
        cs0 += v[0]; cs1 += v[1]; cs2 += v[2]; cs3 += v[3];
    }
    f32x4 wv; wv[0] = cs0; wv[1] = cs1; wv[2] = cs2; wv[3] = cs3;
    *(f32x4*)wp = wv;
}

// ---- reduce col-sum half-strip partials -> wcol; fused BN2 block partials
__global__ void k_wcol_reduce(const float* __restrict__ wcolP,
                              float* __restrict__ wcol, float* __restrict__ ws2) {
    const int t = threadIdx.x;
    int g = blockIdx.x * 256 + t;                    // 24576
    float s = 0.f;
#pragma unroll 8
    for (int strip = 0; strip < 128; strip++)
        s += wcolP[(size_t)strip * 24576 + g];
    wcol[g] = s;
    float a = s, b = s * s;
#pragma unroll
    for (int off = 1; off < 64; off <<= 1) { a += __shfl_xor(a, off); b += __shfl_xor(b, off); }
    __shared__ float sc[4][2];
    if ((t & 63) == 0) { sc[t >> 6][0] = a; sc[t >> 6][1] = b; }
    __syncthreads();
    if (t == 0) {
        ws2[blockIdx.x * 2]     = sc[0][0] + sc[1][0] + sc[2][0] + sc[3][0];
        ws2[blockIdx.x * 2 + 1] = sc[0][1] + sc[1][1] + sc[2][1] + sc[3][1];
    }
}

// ------- tail: BN2 (from block partials) + gate + per-batch softmax
__global__ __launch_bounds__(1024) void k_tail(
        const float* __restrict__ wcol, const float* __restrict__ ws2,
        const unsigned char* __restrict__ bx,
        const float* __restrict__ g2, const float* __restrict__ b2,
        const float* __restrict__ Wp, const float* __restrict__ bp,
        float* __restrict__ wout) {
    const int t = threadIdx.x, lane = t & 63, wv = t >> 6;
    __shared__ float abuf[12];       // a2s[0..5], c2s[6..11]
    __shared__ float xb[4096];
    __shared__ float wred[16][2];

    if (t < HH) {
        float s = 0.f, s2 = 0.f;
        for (int b = 0; b < 4; b++) {
            int bh = b * HH + t;
#pragma unroll
            for (int sub = 0; sub < 4; sub++) {
                int blk = bh * 4 + sub;
                s += ws2[blk * 2];
                s2 += ws2[blk * 2 + 1];
            }
        }
        float m = s / 4096.f;
        float var = fmaxf(s2 / 4096.f - m * m, 0.0f);
        float r = rsqrtf(var + EPS);
        float a = r * g2[t];
        abuf[t] = a;
        abuf[6 + t] = b2[t] - m * a;
    }
    __syncthreads();

    const float bp0 = bp[0], bp1 = bp[1];
#pragma unroll
    for (int p = 0; p < 4; p++) {
        int idx = t + p * 1024;
        int b = idx >> 10, l = idx & 1023;
        float z0 = bp0, z1 = bp1;
#pragma unroll
        for (int h = 0; h < HH; h++) {
            float wn = abuf[h] * wcol[(size_t)(b * HH + h) * 1024 + l] + abuf[6 + h];
            z0 += wn * Wp[h];
            z1 += wn * Wp[HH + h];
        }
        float pc = 1.0f / (1.0f + __expf(z1 - z0));
        xb[idx] = bx[b * LL + l] ? -INFINITY : pc;
    }
    __syncthreads();

    const int bb = t >> 8, tb = t & 255;
    float4 xv = *(const float4*)&xb[bb * 1024 + tb * 4];
    float mx = fmaxf(fmaxf(xv.x, xv.y), fmaxf(xv.z, xv.w));
#pragma unroll
    for (int off = 1; off < 64; off <<= 1) mx = fmaxf(mx, __shfl_xor(mx, off));
    if (lane == 0) wred[wv][0] = mx;
    __syncthreads();
    mx = fmaxf(fmaxf(wred[bb * 4][0], wred[bb * 4 + 1][0]),
               fmaxf(wred[bb * 4 + 2][0], wred[bb * 4 + 3][0]));
    float e0 = __expf(xv.x - mx), e1 = __expf(xv.y - mx);
    float e2 = __expf(xv.z - mx), e3 = __expf(xv.w - mx);
    float ss = e0 + e1 + e2 + e3;
#pragma unroll
    for (int off = 1; off < 64; off <<= 1) ss += __shfl_xor(ss, off);
    if (lane == 0) wred[wv][1] = ss;
    __syncthreads();
    float sum = wred[bb * 4][1] + wred[bb * 4 + 1][1] + wred[bb * 4 + 2][1] + wred[bb * 4 + 3][1];
    float4 o;
    o.x = e0 / sum; o.y = e1 / sum; o.z = e2 / sum; o.w = e3 / sum;
    *(float4*)&wout[bb * 1024 + tb * 4] = o;
}

extern "C" void kernel_launch(void* const* d_in, const int* in_sizes, int n_in,
                              void* d_out, int out_size, void* d_ws, size_t ws_size,
                              hipStream_t stream) {
    const float* Q  = (const float*)d_in[0];
    const float* K  = (const float*)d_in[1];
    const float* V  = (const float*)d_in[2];
    // d_in[3] = pad_mask — derivable from bx_packed, unused
    const unsigned char* bx = (const unsigned char*)d_in[4];
    const float* g1 = (const float*)d_in[5];
    const float* b1 = (const float*)d_in[6];
    const float* g2 = (const float*)d_in[7];
    const float* b2 = (const float*)d_in[8];
    const float* Wp = (const float*)d_in[9];
    const float* bp = (const float*)d_in[10];

    float* out  = (float*)d_out;
    float* co   = out;                        // (B,H,L,L)
    float* wout = out + CO_ELEMS;             // (B,L,1)
    float* vh   = out + CO_ELEMS + W_ELEMS;   // (B,H,L,DH)

    float* ws = (float*)d_ws;                 // ~12.9 MB
    float* q2     = ws + OFF_Q2;
    float* k2     = ws + OFF_K2;
    float* wcol   = ws + OFF_WC;
    float* statsP = ws + OFF_SP;
    float* ac     = ws + OFF_AC;
    float* ws2    = ws + OFF_SS;
    float* wcolP  = ws + OFF_WP;

    float* QTf = co;                          // co region as scratch (pre-fused)

    k_rownorm<<<768, 256, 0, stream>>>(Q, K, ws);
    k_vh<<<3072, 256, 0, stream>>>(V, vh);
    k_tr<<<dim3(8, 24, 2), 256, 0, stream>>>(Q, K, QTf);
    k_moments<<<24, 256, 0, stream>>>(QTf, q2, k2, statsP);
    k_stats2<<<1, 64, 0, stream>>>(statsP, g1, b1, ac);
    k_fused<<<dim3(24, 64), 512, 0, stream>>>(Q, K, q2, k2, ac, bx, co, wcolP);
    k_wcol_reduce<<<96, 256, 0, stream>>>(wcolP, wcol, ws2);
    k_tail<<<1, 1024, 0, stream>>>(wcol, ws2, bx, g2, b2, Wp, bp, wout);
}

// Round 3
// 327.837 us; speedup vs baseline: 1.7683x; 1.7683x over previous
//
#include <hip/hip_runtime.h>
#include <stdint.h>
#include <stddef.h>

// Problem constants (B=4, L=1024, D=768, H=6, DH=128)
#define BB 4
#define LL 1024
#define DD 768
#define HH 6
#define DHH 128
#define EPS 1e-5f

// Output layout (fp32 elements, concatenated in return order):
//   co : (B,H,L,L) = 25165824
//   w  : (B,L,1)   = 4096
//   Vh : (B,H,L,DH)= 3145728
#define CO_ELEMS 25165824
#define W_ELEMS  4096

// ws layout (fp32 elements), ~13.3 MB. All deterministic writes, no atomics.
#define OFF_Q2  0           // 24576
#define OFF_K2  24576       // 24576
#define OFF_WC  49152       // 24576  final col sums
#define OFF_SP  73728       // 48     per-bh {sumS,sumS2} analytic moments
#define OFF_AC  79872       // 16     a1[0..7], c1[8..15]
#define OFF_SS  79888       // 192    BN2 (sum,sumsq) block partials
#define OFF_WP  81920       // 128*24*1024 = 3145728 col-sum half-strip partials
#define OFF_GG  3227648     // 24*36 = 864 (pad 1024) Gram-dot tile partials
#define OFF_MS1 3228672     // 2*24*8*128 = 49152  per-d sum partials
#define OFF_MS2 3277824     // 49152               per-d weighted-sum partials
// total 3326976 floats = 13.31 MB

typedef __attribute__((ext_vector_type(8))) short short8;
typedef __attribute__((ext_vector_type(4))) float f32x4;

// load 8 contiguous fp32, truncate to bf16 fragment
__device__ __forceinline__ short8 ld_bf8(const float* __restrict__ p) {
    const float4 a = *(const float4*)(p);
    const float4 b = *(const float4*)(p + 4);
    short8 r;
    r[0] = (short)(__float_as_uint(a.x) >> 16);
    r[1] = (short)(__float_as_uint(a.y) >> 16);
    r[2] = (short)(__float_as_uint(a.z) >> 16);
    r[3] = (short)(__float_as_uint(a.w) >> 16);
    r[4] = (short)(__float_as_uint(b.x) >> 16);
    r[5] = (short)(__float_as_uint(b.y) >> 16);
    r[6] = (short)(__float_as_uint(b.z) >> 16);
    r[7] = (short)(__float_as_uint(b.w) >> 16);
    return r;
}

// ------------------------------------------------- q2 / k2 (row sq-norms)
__global__ void k_rownorm(const float* __restrict__ Q,
                          const float* __restrict__ K,
                          float* __restrict__ ws) {
    int gid = blockIdx.x * 256 + threadIdx.x;       // 196608
    int sub = gid & 3;
    int rg  = gid >> 2;
    int which = (rg >= 24576);
    int rid = which ? rg - 24576 : rg;              // bh*1024 + i
    int bh = rid >> 10, i = rid & 1023;
    int b = bh / HH, h = bh - b * HH;
    const float* src = (which ? K : Q) + (size_t)(b * LL + i) * DD + h * DHH;
    float s = 0.f;
#pragma unroll
    for (int kk = 0; kk < 8; kk++) {
        float4 v = *(const float4*)(src + (sub + 4 * kk) * 4);
        s += v.x * v.x + v.y * v.y + v.z * v.z + v.w * v.w;
    }
    s += __shfl_xor(s, 1);
    s += __shfl_xor(s, 2);
    if (sub == 0) ws[(which ? OFF_K2 : OFF_Q2) + rid] = s;
}

// ------------------------------------------------- Vh output (exact copy)
__global__ void k_vh(const float* __restrict__ V, float* __restrict__ out) {
    int cid = blockIdx.x * 256 + threadIdx.x;       // 786432 float4 chunks
    if (cid >= 786432) return;
    int d4 = cid & 31;
    int rest = cid >> 5;
    int l = rest & 1023;
    int bh = rest >> 10;
    int b = bh / HH, h = bh - b * HH;
    f32x4 v = *(const f32x4*)(V + (size_t)(b * LL + l) * DD + h * DHH + d4 * 4);
    __builtin_nontemporal_store(v, (f32x4*)(out + (size_t)cid * 4));
}

// ---- per-d truncated sums: sQ[d]=sum_i tq[i][d], sQq2[d]=sum_i tq[i][d]*q2[i]
// (K analog). Deterministic partials over 8 i-chunks. Coalesced row-major reads.
__global__ __launch_bounds__(256) void k_msums(
        const float* __restrict__ Q, const float* __restrict__ K,
        const float* __restrict__ q2, const float* __restrict__ k2,
        float* __restrict__ ms1, float* __restrict__ ms2) {
    const int ic = blockIdx.x;            // 0..7  (128-row i-chunk)
    const int bh = blockIdx.y;            // 0..23
    const int which = blockIdx.z;         // 0=Q, 1=K
    const int b = bh / HH, h = bh - b * HH;
    const float* src = (which ? K : Q) + (size_t)b * LL * DD + h * DHH;
    const float* sc  = (which ? k2 : q2) + bh * 1024;
    const int t = threadIdx.x;
    const int d0 = (t & 31) * 4, ig = t >> 5;      // d-group, i-subgroup

    f32x4 a1 = (f32x4)(0.f), a2 = (f32x4)(0.f);
#pragma unroll 4
    for (int p = 0; p < 16; p++) {
        const int i = ic * 128 + p * 8 + ig;
        float4 v = *(const float4*)(src + (size_t)i * DD + d0);
        f32x4 tv;
        tv[0] = __uint_as_float(__float_as_uint(v.x) & 0xffff0000u);
        tv[1] = __uint_as_float(__float_as_uint(v.y) & 0xffff0000u);
        tv[2] = __uint_as_float(__float_as_uint(v.z) & 0xffff0000u);
        tv[3] = __uint_as_float(__float_as_uint(v.w) & 0xffff0000u);
        const float wgt = sc[i];
        a1[0] += tv[0]; a1[1] += tv[1]; a1[2] += tv[2]; a1[3] += tv[3];
        a2[0] += tv[0] * wgt; a2[1] += tv[1] * wgt; a2[2] += tv[2] * wgt; a2[3] += tv[3] * wgt;
    }
    __shared__ float l1[8][128], l2[8][128];
    *(f32x4*)&l1[ig][d0] = a1;
    *(f32x4*)&l2[ig][d0] = a2;
    __syncthreads();
    const int d = t & 127, sel = t >> 7;
    float s = 0.f;
#pragma unroll
    for (int g = 0; g < 8; g++) s += (sel ? l2 : l1)[g][d];
    float* dst = (sel ? ms2 : ms1);
    dst[((size_t)(which * 24 + bh) * 8 + ic) * 128 + d] = s;
}

// ---- Gram-tile dot partials: ggP[bh][pi] for tile-pair (dt<=et), weight 2
// off-diagonal. Fragments gathered directly from row-major Q/K (truncated),
// 4 waves split K=1024, tiles reduced in LDS BEFORE the <GQ,GK> product.
__global__ __launch_bounds__(256) void k_gramdot(
        const float* __restrict__ Q, const float* __restrict__ K,
        float* __restrict__ ggP) {
    const int pi = blockIdx.x;            // 0..35
    const int bh = blockIdx.y;            // 0..23
    int dt = 0, rem = pi;
    while (rem >= 8 - dt) { rem -= 8 - dt; dt++; }
    const int et = dt + rem;
    const int b = bh / HH, h = bh - b * HH;
    const float* Qb = Q + (size_t)b * LL * DD + h * DHH;
    const float* Kb = K + (size_t)b * LL * DD + h * DHH;
    const int t = threadIdx.x, lane = t & 63, wv = t >> 6;
    const int lm = lane & 15, quad = lane >> 4;
    const int cq = dt * 16 + lm, ce = et * 16 + lm;

    f32x4 aq = (f32x4)(0.f), ak = (f32x4)(0.f);
#pragma unroll
    for (int c = 0; c < 8; c++) {
        const int i0 = wv * 256 + c * 32 + quad * 8;
        short8 qa, qb_, ka, kb_;
#pragma unroll
        for (int e = 0; e < 8; e++) {
            const size_t ro = (size_t)(i0 + e) * DD;
            qa[e]  = (short)(__float_as_uint(Qb[ro + cq]) >> 16);
            qb_[e] = (short)(__float_as_uint(Qb[ro + ce]) >> 16);
            ka[e]  = (short)(__float_as_uint(Kb[ro + cq]) >> 16);
            kb_[e] = (short)(__float_as_uint(Kb[ro + ce]) >> 16);
        }
        aq = __builtin_amdgcn_mfma_f32_16x16x32_bf16(qa, qb_, aq, 0, 0, 0);
        ak = __builtin_amdgcn_mfma_f32_16x16x32_bf16(ka, kb_, ak, 0, 0, 0);
    }
    __shared__ float red[4][64][8];
    *(f32x4*)&red[wv][lane][0] = aq;
    *(f32x4*)&red[wv][lane][4] = ak;
    __syncthreads();
    if (wv == 0) {
        f32x4 AQ = (f32x4)(0.f), AK = (f32x4)(0.f);
#pragma unroll
        for (int w = 0; w < 4; w++) {
            f32x4 x = *(const f32x4*)&red[w][lane][0];
            f32x4 y = *(const f32x4*)&red[w][lane][4];
            AQ[0] += x[0]; AQ[1] += x[1]; AQ[2] += x[2]; AQ[3] += x[3];
            AK[0] += y[0]; AK[1] += y[1]; AK[2] += y[2]; AK[3] += y[3];
        }
        float d4 = AQ[0] * AK[0] + AQ[1] * AK[1] + AQ[2] * AK[2] + AQ[3] * AK[3];
        if (dt != et) d4 *= 2.0f;
#pragma unroll
        for (int off = 1; off < 64; off <<= 1) d4 += __shfl_xor(d4, off);
        if (lane == 0) ggP[bh * 36 + pi] = d4;
    }
}

// ---- assemble analytic BN1 moments per bh:
// sumS  = 2*dA - 1024*(Sq2+Sk2)
// sumS2 = 4*<GQ,GK> + 1024*(Sq2sq+Sk2sq) + 2*Sq2*Sk2 - 4*(dBq+dBk)
__global__ __launch_bounds__(256) void k_stats3(
        const float* __restrict__ ms1, const float* __restrict__ ms2,
        const float* __restrict__ ggP,
        const float* __restrict__ q2, const float* __restrict__ k2,
        float* __restrict__ statsP) {
    const int bh = blockIdx.x;
    const int t = threadIdx.x, lane = t & 63, w = t >> 6;
    __shared__ float sQ[128], sK[128], sQq2[128], sKk2[128];
    __shared__ float sred[4][4];
    __shared__ float gbuf[36];

    {   // per-d chunk reduce
        const int d = t & 127, which = t >> 7;
        const float* p1 = ms1 + (size_t)(which * 24 + bh) * 1024 + d;
        const float* p2 = ms2 + (size_t)(which * 24 + bh) * 1024 + d;
        float s1 = 0.f, s2 = 0.f;
#pragma unroll
        for (int ic = 0; ic < 8; ic++) { s1 += p1[ic * 128]; s2 += p2[ic * 128]; }
        if (which) { sK[d] = s1; sKk2[d] = s2; }
        else       { sQ[d] = s1; sQq2[d] = s2; }
    }
    {   // scalar sums of q2/k2 and squares
        f32x4 qv = *(const f32x4*)(q2 + bh * 1024 + t * 4);
        f32x4 kv = *(const f32x4*)(k2 + bh * 1024 + t * 4);
        float p0 = qv[0] + qv[1] + qv[2] + qv[3];
        float p1 = qv[0]*qv[0] + qv[1]*qv[1] + qv[2]*qv[2] + qv[3]*qv[3];
        float p2 = kv[0] + kv[1] + kv[2] + kv[3];
        float p3 = kv[0]*kv[0] + kv[1]*kv[1] + kv[2]*kv[2] + kv[3]*kv[3];
#pragma unroll
        for (int off = 1; off < 64; off <<= 1) {
            p0 += __shfl_xor(p0, off); p1 += __shfl_xor(p1, off);
            p2 += __shfl_xor(p2, off); p3 += __shfl_xor(p3, off);
        }
        if (lane == 0) { sred[w][0] = p0; sred[w][1] = p1; sred[w][2] = p2; sred[w][3] = p3; }
    }
    if (t < 36) gbuf[t] = ggP[bh * 36 + t];
    __syncthreads();
    if (t < 64) {
        float dA  = sQ[t] * sK[t] + sQ[t + 64] * sK[t + 64];
        float dBq = sQq2[t] * sK[t] + sQq2[t + 64] * sK[t + 64];
        float dBk = sQ[t] * sKk2[t] + sQ[t + 64] * sKk2[t + 64];
#pragma unroll
        for (int off = 1; off < 64; off <<= 1) {
            dA += __shfl_xor(dA, off); dBq += __shfl_xor(dBq, off); dBk += __shfl_xor(dBk, off);
        }
        if (t == 0) {
            float SQ2   = sred[0][0] + sred[1][0] + sred[2][0] + sred[3][0];
            float SQ2SQ = sred[0][1] + sred[1][1] + sred[2][1] + sred[3][1];
            float SK2   = sred[0][2] + sred[1][2] + sred[2][2] + sred[3][2];
            float SK2SQ = sred[0][3] + sred[1][3] + sred[2][3] + sred[3][3];
            float GG = 0.f;
            for (int i = 0; i < 36; i++) GG += gbuf[i];
            float sumS  = 2.f * dA - 1024.f * (SQ2 + SK2);
            float sumS2 = 4.f * GG + 1024.f * (SQ2SQ + SK2SQ) + 2.f * SQ2 * SK2 - 4.f * (dBq + dBk);
            statsP[bh * 2]     = sumS;
            statsP[bh * 2 + 1] = sumS2;
        }
    }
}

// --------------------------------------------- BN1 stats -> ac
__global__ void k_stats2(const float* __restrict__ statsP,
                         const float* __restrict__ g1, const float* __restrict__ b1,
                         float* __restrict__ ac) {
    const int t = threadIdx.x;
    if (t < HH) {
        float T1 = 0.f, T2 = 0.f;
#pragma unroll
        for (int b = 0; b < 4; b++) {
            T1 += statsP[(b * HH + t) * 2];
            T2 += statsP[(b * HH + t) * 2 + 1];
        }
        const float N = 4194304.f;                 // 4*1024*1024
        float m_ = T1 / N;
        float var = fmaxf(T2 / N - m_ * m_, 0.0f);
        float r = rsqrtf(var + EPS);
        float a = r * g1[t];
        ac[t] = a;
        ac[8 + t] = b1[t] - m_ * a;
    }
}

// ---- FUSED: recompute S via MFMA (verified R1 lane math), BN+mask+exp into
// a 16x1024 LDS strip, row-softmax, coalesced 1KB/wave NT stores, half-strip
// col-sum partials. grid.x = bh -> all strips of a bh on one XCD (24%8==0).
__global__ __launch_bounds__(512, 2) void k_fused(
        const float* __restrict__ Q, const float* __restrict__ Km,
        const float* __restrict__ q2, const float* __restrict__ k2,
        const float* __restrict__ ac, const unsigned char* __restrict__ bx,
        float* __restrict__ co, float* __restrict__ wcolP) {
    const int bh = blockIdx.x;            // 24
    const int strip = blockIdx.y;         // 64 strips of 16 rows
    const int b = bh / HH, h = bh - b * HH;
    const int t = threadIdx.x, lane = t & 63, w = t >> 6;   // 8 waves
    const int lm = lane & 15, quad = lane >> 4;
    const int i0 = strip * 16;
    const int jw = w * 128;               // wave's 128-col range

    __shared__ float e_lds[16][1028];     // padded: balanced LDS banks
    __shared__ float rowsum[16];
    if (t < 16) rowsum[t] = 0.f;
    __syncthreads();

    const float* Qb = Q + (size_t)b * LL * DD + h * DHH;
    const float* Kb = Km + (size_t)b * LL * DD + h * DHH;
    const float a1 = ac[h], c1 = ac[8 + h];
    const unsigned char* bxb = bx + b * LL;

    // Q fragments (B-operand): rows i0+lm, k-chunks by quad
    short8 qf[4];
#pragma unroll
    for (int kk = 0; kk < 4; kk++)
        qf[kk] = ld_bf8(Qb + (size_t)(i0 + lm) * DD + kk * 32 + quad * 8);

    const bool vi = (bxb[i0 + lm] == 0);
    const float q2v = q2[bh * 1024 + i0 + lm];

    float rsum = 0.f;
#pragma unroll
    for (int jt = 0; jt < 8; jt++) {
        const int jb = jw + jt * 16;
        short8 kf[4];
#pragma unroll
        for (int kk = 0; kk < 4; kk++)
            kf[kk] = ld_bf8(Kb + (size_t)(jb + lm) * DD + kk * 32 + quad * 8);
        f32x4 acc = (f32x4)(0.0f);
#pragma unroll
        for (int kk = 0; kk < 4; kk++)
            acc = __builtin_amdgcn_mfma_f32_16x16x32_bf16(kf[kk], qf[kk], acc, 0, 0, 0);
        // acc[r]: j = jb + quad*4 + r, i = i0 + lm
        const f32x4 k2v = *(const f32x4*)(k2 + bh * 1024 + jb + quad * 4);
        const uchar4 m4 = *(const uchar4*)(bxb + jb + quad * 4);
        f32x4 ev;
        ev[0] = (vi && m4.x == 0) ? __expf(fminf(a1 * (2.0f * acc[0] - q2v - k2v[0]) + c1, 60.0f)) : 1.0f;
        ev[1] = (vi && m4.y == 0) ? __expf(fminf(a1 * (2.0f * acc[1] - q2v - k2v[1]) + c1, 60.0f)) : 1.0f;
        ev[2] = (vi && m4.z == 0) ? __expf(fminf(a1 * (2.0f * acc[2] - q2v - k2v[2]) + c1, 60.0f)) : 1.0f;
        ev[3] = (vi && m4.w == 0) ? __expf(fminf(a1 * (2.0f * acc[3] - q2v - k2v[3]) + c1, 60.0f)) : 1.0f;
        *(f32x4*)&e_lds[lm][jb + quad * 4] = ev;
        rsum += (ev[0] + ev[1]) + (ev[2] + ev[3]);
    }
    // row-sum: reduce over quads, then across waves via 16 LDS atomics
    rsum += __shfl_xor(rsum, 16);
    rsum += __shfl_xor(rsum, 32);
    if (lane < 16) atomicAdd(&rowsum[lm], rsum);
    __syncthreads();

    // phase B: coalesced scaled stores + half-strip col sums
    const int cg = t & 255, rh = t >> 8;
    float* cob = co + ((size_t)bh << 20) + (size_t)(i0 + rh * 8) * 1024 + cg * 4;
    float* wp = wcolP + ((size_t)((strip * 2 + rh) * 24 + bh)) * 1024 + cg * 4;
    float cs0 = 0.f, cs1 = 0.f, cs2 = 0.f, cs3 = 0.f;
#pragma unroll
    for (int rr = 0; rr < 8; rr++) {
        const int r = rh * 8 + rr;
        const float inv = 1.0f / rowsum[r];
        f32x4 v = *(const f32x4*)&e_lds[r][cg * 4];
        v[0] *= inv; v[1] *= inv; v[2] *= inv; v[3] *= inv;
        __builtin_nontemporal_store(v, (f32x4*)(cob + (size_t)rr * 1024));
        cs0 += v[0]; cs1 += v[1]; cs2 += v[2]; cs3 += v[3];
    }
    f32x4 wv; wv[0] = cs0; wv[1] = cs1; wv[2] = cs2; wv[3] = cs3;
    *(f32x4*)wp = wv;
}

// ---- reduce col-sum half-strip partials -> wcol; fused BN2 block partials
__global__ void k_wcol_reduce(const float* __restrict__ wcolP,
                              float* __restrict__ wcol, float* __restrict__ ws2) {
    const int t = threadIdx.x;
    int g = blockIdx.x * 256 + t;                    // 24576
    float s = 0.f;
#pragma unroll 8
    for (int strip = 0; strip < 128; strip++)
        s += wcolP[(size_t)strip * 24576 + g];
    wcol[g] = s;
    float a = s, b = s * s;
#pragma unroll
    for (int off = 1; off < 64; off <<= 1) { a += __shfl_xor(a, off); b += __shfl_xor(b, off); }
    __shared__ float sc[4][2];
    if ((t & 63) == 0) { sc[t >> 6][0] = a; sc[t >> 6][1] = b; }
    __syncthreads();
    if (t == 0) {
        ws2[blockIdx.x * 2]     = sc[0][0] + sc[1][0] + sc[2][0] + sc[3][0];
        ws2[blockIdx.x * 2 + 1] = sc[0][1] + sc[1][1] + sc[2][1] + sc[3][1];
    }
}

// ------- tail: BN2 (from block partials) + gate + per-batch softmax
__global__ __launch_bounds__(1024) void k_tail(
        const float* __restrict__ wcol, const float* __restrict__ ws2,
        const unsigned char* __restrict__ bx,
        const float* __restrict__ g2, const float* __restrict__ b2,
        const float* __restrict__ Wp, const float* __restrict__ bp,
        float* __restrict__ wout) {
    const int t = threadIdx.x, lane = t & 63, wv = t >> 6;
    __shared__ float abuf[12];       // a2s[0..5], c2s[6..11]
    __shared__ float xb[4096];
    __shared__ float wred[16][2];

    if (t < HH) {
        float s = 0.f, s2 = 0.f;
        for (int b = 0; b < 4; b++) {
            int bh = b * HH + t;
#pragma unroll
            for (int sub = 0; sub < 4; sub++) {
                int blk = bh * 4 + sub;
                s += ws2[blk * 2];
                s2 += ws2[blk * 2 + 1];
            }
        }
        float m = s / 4096.f;
        float var = fmaxf(s2 / 4096.f - m * m, 0.0f);
        float r = rsqrtf(var + EPS);
        float a = r * g2[t];
        abuf[t] = a;
        abuf[6 + t] = b2[t] - m * a;
    }
    __syncthreads();

    const float bp0 = bp[0], bp1 = bp[1];
#pragma unroll
    for (int p = 0; p < 4; p++) {
        int idx = t + p * 1024;
        int b = idx >> 10, l = idx & 1023;
        float z0 = bp0, z1 = bp1;
#pragma unroll
        for (int h = 0; h < HH; h++) {
            float wn = abuf[h] * wcol[(size_t)(b * HH + h) * 1024 + l] + abuf[6 + h];
            z0 += wn * Wp[h];
            z1 += wn * Wp[HH + h];
        }
        float pc = 1.0f / (1.0f + __expf(z1 - z0));
        xb[idx] = bx[b * LL + l] ? -INFINITY : pc;
    }
    __syncthreads();

    const int bb = t >> 8, tb = t & 255;
    float4 xv = *(const float4*)&xb[bb * 1024 + tb * 4];
    float mx = fmaxf(fmaxf(xv.x, xv.y), fmaxf(xv.z, xv.w));
#pragma unroll
    for (int off = 1; off < 64; off <<= 1) mx = fmaxf(mx, __shfl_xor(mx, off));
    if (lane == 0) wred[wv][0] = mx;
    __syncthreads();
    mx = fmaxf(fmaxf(wred[bb * 4][0], wred[bb * 4 + 1][0]),
               fmaxf(wred[bb * 4 + 2][0], wred[bb * 4 + 3][0]));
    float e0 = __expf(xv.x - mx), e1 = __expf(xv.y - mx);
    float e2 = __expf(xv.z - mx), e3 = __expf(xv.w - mx);
    float ss = e0 + e1 + e2 + e3;
#pragma unroll
    for (int off = 1; off < 64; off <<= 1) ss += __shfl_xor(ss, off);
    if (lane == 0) wred[wv][1] = ss;
    __syncthreads();
    float sum = wred[bb * 4][1] + wred[bb * 4 + 1][1] + wred[bb * 4 + 2][1] + wred[bb * 4 + 3][1];
    float4 o;
    o.x = e0 / sum; o.y = e1 / sum; o.z = e2 / sum; o.w = e3 / sum;
    *(float4*)&wout[bb * 1024 + tb * 4] = o;
}

extern "C" void kernel_launch(void* const* d_in, const int* in_sizes, int n_in,
                              void* d_out, int out_size, void* d_ws, size_t ws_size,
                              hipStream_t stream) {
    const float* Q  = (const float*)d_in[0];
    const float* K  = (const float*)d_in[1];
    const float* V  = (const float*)d_in[2];
    // d_in[3] = pad_mask — derivable from bx_packed, unused
    const unsigned char* bx = (const unsigned char*)d_in[4];
    const float* g1 = (const float*)d_in[5];
    const float* b1 = (const float*)d_in[6];
    const float* g2 = (const float*)d_in[7];
    const float* b2 = (const float*)d_in[8];
    const float* Wp = (const float*)d_in[9];
    const float* bp = (const float*)d_in[10];

    float* out  = (float*)d_out;
    float* co   = out;                        // (B,H,L,L)
    float* wout = out + CO_ELEMS;             // (B,L,1)
    float* vh   = out + CO_ELEMS + W_ELEMS;   // (B,H,L,DH)

    float* ws = (float*)d_ws;                 // ~13.3 MB
    float* q2     = ws + OFF_Q2;
    float* k2     = ws + OFF_K2;
    float* wcol   = ws + OFF_WC;
    float* statsP = ws + OFF_SP;
    float* ac     = ws + OFF_AC;
    float* ws2    = ws + OFF_SS;
    float* wcolP  = ws + OFF_WP;
    float* ggP    = ws + OFF_GG;
    float* ms1    = ws + OFF_MS1;
    float* ms2    = ws + OFF_MS2;

    k_rownorm<<<768, 256, 0, stream>>>(Q, K, ws);
    k_vh<<<3072, 256, 0, stream>>>(V, vh);
    k_msums<<<dim3(8, 24, 2), 256, 0, stream>>>(Q, K, q2, k2, ms1, ms2);
    k_gramdot<<<dim3(36, 24), 256, 0, stream>>>(Q, K, ggP);
    k_stats3<<<24, 256, 0, stream>>>(ms1, ms2, ggP, q2, k2, statsP);
    k_stats2<<<1, 64, 0, stream>>>(statsP, g1, b1, ac);
    k_fused<<<dim3(24, 64), 512, 0, stream>>>(Q, K, q2, k2, ac, bx, co, wcolP);
    k_wcol_reduce<<<96, 256, 0, stream>>>(wcolP, wcol, ws2);
    k_tail<<<1, 1024, 0, stream>>>(wcol, ws2, bx, g2, b2, Wp, bp, wout);
}

// Round 4
// 269.920 us; speedup vs baseline: 2.1477x; 1.2146x over previous
//
#include <hip/hip_runtime.h>
#include <stdint.h>
#include <stddef.h>

// Problem constants (B=4, L=1024, D=768, H=6, DH=128)
#define BB 4
#define LL 1024
#define DD 768
#define HH 6
#define DHH 128
#define EPS 1e-5f

// Output layout (fp32 elements, concatenated in return order):
//   co : (B,H,L,L) = 25165824
//   w  : (B,L,1)   = 4096
//   Vh : (B,H,L,DH)= 3145728
#define CO_ELEMS 25165824
#define W_ELEMS  4096

// ws layout (fp32 elements), ~21.2 MB. All deterministic writes, no atomics.
#define OFF_Q2  0           // 24576
#define OFF_K2  24576       // 24576
#define OFF_WC  49152       // 24576  final col sums
#define OFF_SP  73728       // 48     per-bh {sumS,sumS2} analytic moments
#define OFF_AC  79872       // 16     a1[0..7], c1[8..15]
#define OFF_SS  79888       // 192    BN2 (sum,sumsq) block partials
#define OFF_WP  81920       // 64*24*1024 = 1572864 col-sum half-strip partials
#define OFF_GP  1654784     // 2*24*8*36*256 = 3538944 Gram tile chunk partials
#define OFF_MS1 5193728     // 2*24*8*128 = 49152  per-d sum partials
#define OFF_MS2 5242880     // 49152               per-d weighted-sum partials
// total 5292032 floats = 21.2 MB

typedef __attribute__((ext_vector_type(8))) short short8;
typedef __attribute__((ext_vector_type(4))) float f32x4;

// load 8 contiguous fp32, truncate to bf16 fragment
__device__ __forceinline__ short8 ld_bf8(const float* __restrict__ p) {
    const float4 a = *(const float4*)(p);
    const float4 b = *(const float4*)(p + 4);
    short8 r;
    r[0] = (short)(__float_as_uint(a.x) >> 16);
    r[1] = (short)(__float_as_uint(a.y) >> 16);
    r[2] = (short)(__float_as_uint(a.z) >> 16);
    r[3] = (short)(__float_as_uint(a.w) >> 16);
    r[4] = (short)(__float_as_uint(b.x) >> 16);
    r[5] = (short)(__float_as_uint(b.y) >> 16);
    r[6] = (short)(__float_as_uint(b.z) >> 16);
    r[7] = (short)(__float_as_uint(b.w) >> 16);
    return r;
}

// ------------------------------------------------- Vh output (exact copy)
__global__ void k_vh(const float* __restrict__ V, float* __restrict__ out) {
    int cid = blockIdx.x * 256 + threadIdx.x;       // 786432 float4 chunks
    if (cid >= 786432) return;
    int d4 = cid & 31;
    int rest = cid >> 5;
    int l = rest & 1023;
    int bh = rest >> 10;
    int b = bh / HH, h = bh - b * HH;
    f32x4 v = *(const f32x4*)(V + (size_t)(b * LL + l) * DD + h * DHH + d4 * 4);
    __builtin_nontemporal_store(v, (f32x4*)(out + (size_t)cid * 4));
}

// ---- PREP (fused rownorm + msums + gram partials), per (chunk, bh, which):
// stages 128x128 truncated chunk TRANSPOSED in LDS, computes:
//   q2/k2 rows (untruncated fp32), ms1[d]=sum_i tq, ms2[d]=sum_i tq*q2,
//   per-chunk Gram tiles G[dt][et] via MFMA (weight 2 off-diag folded to Q side)
__global__ __launch_bounds__(256) void k_gram(
        const float* __restrict__ Q, const float* __restrict__ K,
        float* __restrict__ ws, float* __restrict__ gramP,
        float* __restrict__ ms1, float* __restrict__ ms2) {
    const int ic = blockIdx.x;            // 0..7
    const int bh = blockIdx.y;            // 0..23
    const int which = blockIdx.z;         // 0=Q, 1=K
    const int b = bh / HH, h = bh - b * HH;
    const float* src = (which ? K : Q) + (size_t)b * LL * DD + h * DHH;
    float* sqout = ws + (which ? OFF_K2 : OFF_Q2) + bh * 1024 + ic * 128;

    const int t = threadIdx.x, lane = t & 63, wv = t >> 6;
    const int lm = lane & 15, quad = lane >> 4;

    __shared__ float tileT[128][129];     // [d][i] truncated fp32
    __shared__ float q2loc[128];

    // ---- stage + per-row sq-norm
    const int ig = t >> 5;                 // 0..7 (row subgroup)
    const int d0 = (t & 31) * 4;
#pragma unroll 4
    for (int p = 0; p < 16; p++) {
        const int i_loc = p * 8 + ig;
        float4 v = *(const float4*)(src + (size_t)(ic * 128 + i_loc) * DD + d0);
        tileT[d0 + 0][i_loc] = __uint_as_float(__float_as_uint(v.x) & 0xffff0000u);
        tileT[d0 + 1][i_loc] = __uint_as_float(__float_as_uint(v.y) & 0xffff0000u);
        tileT[d0 + 2][i_loc] = __uint_as_float(__float_as_uint(v.z) & 0xffff0000u);
        tileT[d0 + 3][i_loc] = __uint_as_float(__float_as_uint(v.w) & 0xffff0000u);
        float s = v.x * v.x + v.y * v.y + v.z * v.z + v.w * v.w;
#pragma unroll
        for (int off = 1; off < 32; off <<= 1) s += __shfl_xor(s, off);
        if ((t & 31) == 0) { q2loc[i_loc] = s; sqout[i_loc] = s; }
    }
    __syncthreads();

    // ---- per-d sums over this chunk
    if (t < 128) {
        float s1 = 0.f, s2 = 0.f;
#pragma unroll 8
        for (int i = 0; i < 128; i++) {
            float v = tileT[t][i];
            s1 += v;
            s2 += v * q2loc[i];
        }
        const size_t mo = ((size_t)(which * 24 + bh) * 8 + ic) * 128 + t;
        ms1[mo] = s1;
        ms2[mo] = s2;
    }

    // ---- Gram tile partials: pairs pi with pi%4==wv (9 per wave)
    const size_t gbase = ((size_t)(which * 24 + bh) * 8 + ic) * 9216;
    int pi = 0;
    for (int dt = 0; dt < 8; dt++) {
        for (int et = dt; et < 8; et++, pi++) {
            if ((pi & 3) != wv) continue;
            f32x4 acc = (f32x4)(0.0f);
#pragma unroll
            for (int kk = 0; kk < 4; kk++) {
                const int i0 = kk * 32 + quad * 8;
                const float* pa = &tileT[dt * 16 + lm][i0];
                const float* pb = &tileT[et * 16 + lm][i0];
                short8 af, bf;
#pragma unroll
                for (int e = 0; e < 8; e++) {
                    af[e] = (short)(__float_as_uint(pa[e]) >> 16);
                    bf[e] = (short)(__float_as_uint(pb[e]) >> 16);
                }
                acc = __builtin_amdgcn_mfma_f32_16x16x32_bf16(af, bf, acc, 0, 0, 0);
            }
            if (dt != et && which == 0) {
                acc[0] *= 2.f; acc[1] *= 2.f; acc[2] *= 2.f; acc[3] *= 2.f;
            }
            *(f32x4*)&gramP[gbase + (size_t)pi * 256 + lane * 4] = acc;
        }
    }
}

// ---- assemble analytic BN1 moments per bh:
// sumS  = 2*dA - 1024*(Sq2+Sk2)
// sumS2 = 4*GG + 1024*(Sq2sq+Sk2sq) + 2*Sq2*Sk2 - 4*(dBq+dBk)
__global__ __launch_bounds__(256) void k_stats3(
        const float* __restrict__ ms1, const float* __restrict__ ms2,
        const float* __restrict__ gramP,
        const float* __restrict__ q2, const float* __restrict__ k2,
        float* __restrict__ statsP) {
    const int bh = blockIdx.x;
    const int t = threadIdx.x, lane = t & 63, w = t >> 6;
    __shared__ float sQ[128], sK[128], sQq2[128], sKk2[128];
    __shared__ float sred[4][4];
    __shared__ float gred[4];

    {   // per-d chunk reduce
        const int d = t & 127, which = t >> 7;
        const float* p1 = ms1 + (size_t)(which * 24 + bh) * 1024 + d;
        const float* p2 = ms2 + (size_t)(which * 24 + bh) * 1024 + d;
        float s1 = 0.f, s2 = 0.f;
#pragma unroll
        for (int ic = 0; ic < 8; ic++) { s1 += p1[ic * 128]; s2 += p2[ic * 128]; }
        if (which) { sK[d] = s1; sKk2[d] = s2; }
        else       { sQ[d] = s1; sQq2[d] = s2; }
    }
    {   // scalar sums of q2/k2 and squares
        f32x4 qv = *(const f32x4*)(q2 + bh * 1024 + t * 4);
        f32x4 kv = *(const f32x4*)(k2 + bh * 1024 + t * 4);
        float p0 = qv[0] + qv[1] + qv[2] + qv[3];
        float p1 = qv[0]*qv[0] + qv[1]*qv[1] + qv[2]*qv[2] + qv[3]*qv[3];
        float p2 = kv[0] + kv[1] + kv[2] + kv[3];
        float p3 = kv[0]*kv[0] + kv[1]*kv[1] + kv[2]*kv[2] + kv[3]*kv[3];
#pragma unroll
        for (int off = 1; off < 64; off <<= 1) {
            p0 += __shfl_xor(p0, off); p1 += __shfl_xor(p1, off);
            p2 += __shfl_xor(p2, off); p3 += __shfl_xor(p3, off);
        }
        if (lane == 0) { sred[w][0] = p0; sred[w][1] = p1; sred[w][2] = p2; sred[w][3] = p3; }
    }
    {   // GG = sum over pairs/elems of GQ'(weighted) * GK, chunks reduced first
        const float* gq = gramP + (size_t)(0 * 24 + bh) * 8 * 9216;
        const float* gk = gramP + (size_t)(1 * 24 + bh) * 8 * 9216;
        float gg = 0.f;
        for (int pi = 0; pi < 36; pi++) {
            const size_t o = (size_t)pi * 256 + t;
            float a = 0.f, c = 0.f;
#pragma unroll
            for (int icc = 0; icc < 8; icc++) {
                a += gq[(size_t)icc * 9216 + o];
                c += gk[(size_t)icc * 9216 + o];
            }
            gg += a * c;
        }
#pragma unroll
        for (int off = 1; off < 64; off <<= 1) gg += __shfl_xor(gg, off);
        if (lane == 0) gred[w] = gg;
    }
    __syncthreads();
    if (t < 64) {
        float dA  = sQ[t] * sK[t] + sQ[t + 64] * sK[t + 64];
        float dBq = sQq2[t] * sK[t] + sQq2[t + 64] * sK[t + 64];
        float dBk = sQ[t] * sKk2[t] + sQ[t + 64] * sKk2[t + 64];
#pragma unroll
        for (int off = 1; off < 64; off <<= 1) {
            dA += __shfl_xor(dA, off); dBq += __shfl_xor(dBq, off); dBk += __shfl_xor(dBk, off);
        }
        if (t == 0) {
            float SQ2   = sred[0][0] + sred[1][0] + sred[2][0] + sred[3][0];
            float SQ2SQ = sred[0][1] + sred[1][1] + sred[2][1] + sred[3][1];
            float SK2   = sred[0][2] + sred[1][2] + sred[2][2] + sred[3][2];
            float SK2SQ = sred[0][3] + sred[1][3] + sred[2][3] + sred[3][3];
            float GG = gred[0] + gred[1] + gred[2] + gred[3];
            float sumS  = 2.f * dA - 1024.f * (SQ2 + SK2);
            float sumS2 = 4.f * GG + 1024.f * (SQ2SQ + SK2SQ) + 2.f * SQ2 * SK2 - 4.f * (dBq + dBk);
            statsP[bh * 2]     = sumS;
            statsP[bh * 2 + 1] = sumS2;
        }
    }
}

// --------------------------------------------- BN1 stats -> ac
__global__ void k_stats2(const float* __restrict__ statsP,
                         const float* __restrict__ g1, const float* __restrict__ b1,
                         float* __restrict__ ac) {
    const int t = threadIdx.x;
    if (t < HH) {
        float T1 = 0.f, T2 = 0.f;
#pragma unroll
        for (int b = 0; b < 4; b++) {
            T1 += statsP[(b * HH + t) * 2];
            T2 += statsP[(b * HH + t) * 2 + 1];
        }
        const float N = 4194304.f;                 // 4*1024*1024
        float m_ = T1 / N;
        float var = fmaxf(T2 / N - m_ * m_, 0.0f);
        float r = rsqrtf(var + EPS);
        float a = r * g1[t];
        ac[t] = a;
        ac[8 + t] = b1[t] - m_ * a;
    }
}

// ---- FUSED: recompute S via MFMA (verified R1/R3 lane math), 32 rows/block:
// kf loaded once per jt feeds TWO q-row-sets -> K L2/L3 traffic halved.
// BN+mask+exp into 32x1024 LDS strip, row softmax, coalesced NT stores,
// half-strip col-sum partials. grid.x = bh -> XCD affinity (24%8==0).
__global__ __launch_bounds__(512, 1) void k_fused(
        const float* __restrict__ Q, const float* __restrict__ Km,
        const float* __restrict__ q2, const float* __restrict__ k2,
        const float* __restrict__ ac, const unsigned char* __restrict__ bx,
        float* __restrict__ co, float* __restrict__ wcolP) {
    const int bh = blockIdx.x;            // 24
    const int strip = blockIdx.y;         // 32 strips of 32 rows
    const int b = bh / HH, h = bh - b * HH;
    const int t = threadIdx.x, lane = t & 63, w = t >> 6;   // 8 waves
    const int lm = lane & 15, quad = lane >> 4;
    const int i0 = strip * 32;
    const int jw = w * 128;               // wave's 128-col range

    __shared__ float e_lds[32][1028];     // padded: balanced LDS banks
    __shared__ float rowsum[32];
    if (t < 32) rowsum[t] = 0.f;
    __syncthreads();

    const float* Qb = Q + (size_t)b * LL * DD + h * DHH;
    const float* Kb = Km + (size_t)b * LL * DD + h * DHH;
    const float a1 = ac[h], c1 = ac[8 + h];
    const unsigned char* bxb = bx + b * LL;

    // Q fragments (B-operand): two row-sets i0+s*16+lm, k-chunks by quad
    short8 qf[2][4];
#pragma unroll
    for (int s = 0; s < 2; s++)
#pragma unroll
        for (int kk = 0; kk < 4; kk++)
            qf[s][kk] = ld_bf8(Qb + (size_t)(i0 + s * 16 + lm) * DD + kk * 32 + quad * 8);

    bool vi[2];
    float q2v[2];
#pragma unroll
    for (int s = 0; s < 2; s++) {
        vi[s] = (bxb[i0 + s * 16 + lm] == 0);
        q2v[s] = q2[bh * 1024 + i0 + s * 16 + lm];
    }

    float rsum0 = 0.f, rsum1 = 0.f;
#pragma unroll
    for (int jt = 0; jt < 8; jt++) {
        const int jb = jw + jt * 16;
        short8 kf[4];
#pragma unroll
        for (int kk = 0; kk < 4; kk++)
            kf[kk] = ld_bf8(Kb + (size_t)(jb + lm) * DD + kk * 32 + quad * 8);
        f32x4 acc0 = (f32x4)(0.0f), acc1 = (f32x4)(0.0f);
#pragma unroll
        for (int kk = 0; kk < 4; kk++) {
            acc0 = __builtin_amdgcn_mfma_f32_16x16x32_bf16(kf[kk], qf[0][kk], acc0, 0, 0, 0);
            acc1 = __builtin_amdgcn_mfma_f32_16x16x32_bf16(kf[kk], qf[1][kk], acc1, 0, 0, 0);
        }
        // acc[r]: j = jb + quad*4 + r, i = i0 + s*16 + lm
        const f32x4 k2v = *(const f32x4*)(k2 + bh * 1024 + jb + quad * 4);
        const uchar4 m4 = *(const uchar4*)(bxb + jb + quad * 4);
        const bool vj0 = (m4.x == 0), vj1 = (m4.y == 0), vj2 = (m4.z == 0), vj3 = (m4.w == 0);
        {
            f32x4 ev;
            ev[0] = (vi[0] && vj0) ? __expf(fminf(a1 * (2.0f * acc0[0] - q2v[0] - k2v[0]) + c1, 60.0f)) : 1.0f;
            ev[1] = (vi[0] && vj1) ? __expf(fminf(a1 * (2.0f * acc0[1] - q2v[0] - k2v[1]) + c1, 60.0f)) : 1.0f;
            ev[2] = (vi[0] && vj2) ? __expf(fminf(a1 * (2.0f * acc0[2] - q2v[0] - k2v[2]) + c1, 60.0f)) : 1.0f;
            ev[3] = (vi[0] && vj3) ? __expf(fminf(a1 * (2.0f * acc0[3] - q2v[0] - k2v[3]) + c1, 60.0f)) : 1.0f;
            *(f32x4*)&e_lds[lm][jb + quad * 4] = ev;
            rsum0 += (ev[0] + ev[1]) + (ev[2] + ev[3]);
        }
        {
            f32x4 ev;
            ev[0] = (vi[1] && vj0) ? __expf(fminf(a1 * (2.0f * acc1[0] - q2v[1] - k2v[0]) + c1, 60.0f)) : 1.0f;
            ev[1] = (vi[1] && vj1) ? __expf(fminf(a1 * (2.0f * acc1[1] - q2v[1] - k2v[1]) + c1, 60.0f)) : 1.0f;
            ev[2] = (vi[1] && vj2) ? __expf(fminf(a1 * (2.0f * acc1[2] - q2v[1] - k2v[2]) + c1, 60.0f)) : 1.0f;
            ev[3] = (vi[1] && vj3) ? __expf(fminf(a1 * (2.0f * acc1[3] - q2v[1] - k2v[3]) + c1, 60.0f)) : 1.0f;
            *(f32x4*)&e_lds[16 + lm][jb + quad * 4] = ev;
            rsum1 += (ev[0] + ev[1]) + (ev[2] + ev[3]);
        }
    }
    // row-sum: reduce over quads, then across waves via LDS atomics
    rsum0 += __shfl_xor(rsum0, 16);
    rsum0 += __shfl_xor(rsum0, 32);
    rsum1 += __shfl_xor(rsum1, 16);
    rsum1 += __shfl_xor(rsum1, 32);
    if (lane < 16) {
        atomicAdd(&rowsum[lm], rsum0);
        atomicAdd(&rowsum[16 + lm], rsum1);
    }
    __syncthreads();

    // phase B: coalesced scaled stores + half-strip col sums
    const int cg = t & 255, rh = t >> 8;
    float* cob = co + ((size_t)bh << 20) + (size_t)(i0 + rh * 16) * 1024 + cg * 4;
    float* wp = wcolP + ((size_t)((strip * 2 + rh) * 24 + bh)) * 1024 + cg * 4;
    float cs0 = 0.f, cs1 = 0.f, cs2 = 0.f, cs3 = 0.f;
#pragma unroll
    for (int rr = 0; rr < 16; rr++) {
        const int r = rh * 16 + rr;
        const float inv = 1.0f / rowsum[r];
        f32x4 v = *(const f32x4*)&e_lds[r][cg * 4];
        v[0] *= inv; v[1] *= inv; v[2] *= inv; v[3] *= inv;
        __builtin_nontemporal_store(v, (f32x4*)(cob + (size_t)rr * 1024));
        cs0 += v[0]; cs1 += v[1]; cs2 += v[2]; cs3 += v[3];
    }
    f32x4 wv; wv[0] = cs0; wv[1] = cs1; wv[2] = cs2; wv[3] = cs3;
    *(f32x4*)wp = wv;
}

// ---- reduce col-sum half-strip partials -> wcol; fused BN2 block partials
__global__ void k_wcol_reduce(const float* __restrict__ wcolP,
                              float* __restrict__ wcol, float* __restrict__ ws2) {
    const int t = threadIdx.x;
    int g = blockIdx.x * 256 + t;                    // 24576
    float s = 0.f;
#pragma unroll 8
    for (int strip = 0; strip < 64; strip++)
        s += wcolP[(size_t)strip * 24576 + g];
    wcol[g] = s;
    float a = s, b = s * s;
#pragma unroll
    for (int off = 1; off < 64; off <<= 1) { a += __shfl_xor(a, off); b += __shfl_xor(b, off); }
    __shared__ float sc[4][2];
    if ((t & 63) == 0) { sc[t >> 6][0] = a; sc[t >> 6][1] = b; }
    __syncthreads();
    if (t == 0) {
        ws2[blockIdx.x * 2]     = sc[0][0] + sc[1][0] + sc[2][0] + sc[3][0];
        ws2[blockIdx.x * 2 + 1] = sc[0][1] + sc[1][1] + sc[2][1] + sc[3][1];
    }
}

// ------- tail: BN2 (from block partials) + gate + per-batch softmax
__global__ __launch_bounds__(1024) void k_tail(
        const float* __restrict__ wcol, const float* __restrict__ ws2,
        const unsigned char* __restrict__ bx,
        const float* __restrict__ g2, const float* __restrict__ b2,
        const float* __restrict__ Wp, const float* __restrict__ bp,
        float* __restrict__ wout) {
    const int t = threadIdx.x, lane = t & 63, wv = t >> 6;
    __shared__ float abuf[12];       // a2s[0..5], c2s[6..11]
    __shared__ float xb[4096];
    __shared__ float wred[16][2];

    if (t < HH) {
        float s = 0.f, s2 = 0.f;
        for (int b = 0; b < 4; b++) {
            int bh = b * HH + t;
#pragma unroll
            for (int sub = 0; sub < 4; sub++) {
                int blk = bh * 4 + sub;
                s += ws2[blk * 2];
                s2 += ws2[blk * 2 + 1];
            }
        }
        float m = s / 4096.f;
        float var = fmaxf(s2 / 4096.f - m * m, 0.0f);
        float r = rsqrtf(var + EPS);
        float a = r * g2[t];
        abuf[t] = a;
        abuf[6 + t] = b2[t] - m * a;
    }
    __syncthreads();

    const float bp0 = bp[0], bp1 = bp[1];
#pragma unroll
    for (int p = 0; p < 4; p++) {
        int idx = t + p * 1024;
        int b = idx >> 10, l = idx & 1023;
        float z0 = bp0, z1 = bp1;
#pragma unroll
        for (int h = 0; h < HH; h++) {
            float wn = abuf[h] * wcol[(size_t)(b * HH + h) * 1024 + l] + abuf[6 + h];
            z0 += wn * Wp[h];
            z1 += wn * Wp[HH + h];
        }
        float pc = 1.0f / (1.0f + __expf(z1 - z0));
        xb[idx] = bx[b * LL + l] ? -INFINITY : pc;
    }
    __syncthreads();

    const int bb = t >> 8, tb = t & 255;
    float4 xv = *(const float4*)&xb[bb * 1024 + tb * 4];
    float mx = fmaxf(fmaxf(xv.x, xv.y), fmaxf(xv.z, xv.w));
#pragma unroll
    for (int off = 1; off < 64; off <<= 1) mx = fmaxf(mx, __shfl_xor(mx, off));
    if (lane == 0) wred[wv][0] = mx;
    __syncthreads();
    mx = fmaxf(fmaxf(wred[bb * 4][0], wred[bb * 4 + 1][0]),
               fmaxf(wred[bb * 4 + 2][0], wred[bb * 4 + 3][0]));
    float e0 = __expf(xv.x - mx), e1 = __expf(xv.y - mx);
    float e2 = __expf(xv.z - mx), e3 = __expf(xv.w - mx);
    float ss = e0 + e1 + e2 + e3;
#pragma unroll
    for (int off = 1; off < 64; off <<= 1) ss += __shfl_xor(ss, off);
    if (lane == 0) wred[wv][1] = ss;
    __syncthreads();
    float sum = wred[bb * 4][1] + wred[bb * 4 + 1][1] + wred[bb * 4 + 2][1] + wred[bb * 4 + 3][1];
    float4 o;
    o.x = e0 / sum; o.y = e1 / sum; o.z = e2 / sum; o.w = e3 / sum;
    *(float4*)&wout[bb * 1024 + tb * 4] = o;
}

extern "C" void kernel_launch(void* const* d_in, const int* in_sizes, int n_in,
                              void* d_out, int out_size, void* d_ws, size_t ws_size,
                              hipStream_t stream) {
    const float* Q  = (const float*)d_in[0];
    const float* K  = (const float*)d_in[1];
    const float* V  = (const float*)d_in[2];
    // d_in[3] = pad_mask — derivable from bx_packed, unused
    const unsigned char* bx = (const unsigned char*)d_in[4];
    const float* g1 = (const float*)d_in[5];
    const float* b1 = (const float*)d_in[6];
    const float* g2 = (const float*)d_in[7];
    const float* b2 = (const float*)d_in[8];
    const float* Wp = (const float*)d_in[9];
    const float* bp = (const float*)d_in[10];

    float* out  = (float*)d_out;
    float* co   = out;                        // (B,H,L,L)
    float* wout = out + CO_ELEMS;             // (B,L,1)
    float* vh   = out + CO_ELEMS + W_ELEMS;   // (B,H,L,DH)

    float* ws = (float*)d_ws;                 // ~21.2 MB
    float* q2     = ws + OFF_Q2;
    float* k2     = ws + OFF_K2;
    float* wcol   = ws + OFF_WC;
    float* statsP = ws + OFF_SP;
    float* ac     = ws + OFF_AC;
    float* ws2    = ws + OFF_SS;
    float* wcolP  = ws + OFF_WP;
    float* gramP  = ws + OFF_GP;
    float* ms1    = ws + OFF_MS1;
    float* ms2    = ws + OFF_MS2;

    k_gram<<<dim3(8, 24, 2), 256, 0, stream>>>(Q, K, ws, gramP, ms1, ms2);
    k_vh<<<3072, 256, 0, stream>>>(V, vh);
    k_stats3<<<24, 256, 0, stream>>>(ms1, ms2, gramP, q2, k2, statsP);
    k_stats2<<<1, 64, 0, stream>>>(statsP, g1, b1, ac);
    k_fused<<<dim3(24, 32), 512, 0, stream>>>(Q, K, q2, k2, ac, bx, co, wcolP);
    k_wcol_reduce<<<96, 256, 0, stream>>>(wcolP, wcol, ws2);
    k_tail<<<1, 1024, 0, stream>>>(wcol, ws2, bx, g2, b2, Wp, bp, wout);
}

// Round 5
// 259.396 us; speedup vs baseline: 2.2349x; 1.0406x over previous
//
#include <hip/hip_runtime.h>
#include <stdint.h>
#include <stddef.h>

// Problem constants (B=4, L=1024, D=768, H=6, DH=128)
#define BB 4
#define LL 1024
#define DD 768
#define HH 6
#define DHH 128
#define EPS 1e-5f
#define LOG2E 1.44269504088896f

// Output layout (fp32 elements, concatenated in return order):
//   co : (B,H,L,L) = 25165824
//   w  : (B,L,1)   = 4096
//   Vh : (B,H,L,DH)= 3145728
#define CO_ELEMS 25165824
#define W_ELEMS  4096

// ws layout (fp32 elements), ~21.2 MB. All deterministic writes, no atomics.
#define OFF_Q2  0           // 24576
#define OFF_K2  24576       // 24576
#define OFF_WC  49152       // 24576  final col sums
#define OFF_SP  73728       // 48     per-bh {sumS,sumS2} analytic moments
#define OFF_AC  79872       // 16     a1[0..7], c1[8..15]
#define OFF_SS  79888       // 192    BN2 (sum,sumsq) block partials
#define OFF_WP  81920       // 64*24*1024 = 1572864 col-sum half-strip partials
#define OFF_GP  1654784     // 2*24*8*36*256 = 3538944 Gram tile chunk partials
#define OFF_MS1 5193728     // 2*24*8*128 = 49152  per-d sum partials
#define OFF_MS2 5242880     // 49152               per-d weighted-sum partials
// total 5292032 floats = 21.2 MB

typedef __attribute__((ext_vector_type(8))) short short8;
typedef __attribute__((ext_vector_type(4))) float f32x4;

// load 8 contiguous fp32, truncate to bf16 fragment
__device__ __forceinline__ short8 ld_bf8(const float* __restrict__ p) {
    const float4 a = *(const float4*)(p);
    const float4 b = *(const float4*)(p + 4);
    short8 r;
    r[0] = (short)(__float_as_uint(a.x) >> 16);
    r[1] = (short)(__float_as_uint(a.y) >> 16);
    r[2] = (short)(__float_as_uint(a.z) >> 16);
    r[3] = (short)(__float_as_uint(a.w) >> 16);
    r[4] = (short)(__float_as_uint(b.x) >> 16);
    r[5] = (short)(__float_as_uint(b.y) >> 16);
    r[6] = (short)(__float_as_uint(b.z) >> 16);
    r[7] = (short)(__float_as_uint(b.w) >> 16);
    return r;
}

__device__ __forceinline__ short8 pack_bf8(float4 a, float4 b) {
    short8 r;
    r[0] = (short)(__float_as_uint(a.x) >> 16);
    r[1] = (short)(__float_as_uint(a.y) >> 16);
    r[2] = (short)(__float_as_uint(a.z) >> 16);
    r[3] = (short)(__float_as_uint(a.w) >> 16);
    r[4] = (short)(__float_as_uint(b.x) >> 16);
    r[5] = (short)(__float_as_uint(b.y) >> 16);
    r[6] = (short)(__float_as_uint(b.z) >> 16);
    r[7] = (short)(__float_as_uint(b.w) >> 16);
    return r;
}

// ---- PREP (fused rownorm + msums + gram partials + Vh copy).
// grid (8, 24, 3): z=0 Q-side, z=1 K-side, z=2 Vh copy chunk.
__global__ __launch_bounds__(256) void k_gram(
        const float* __restrict__ Q, const float* __restrict__ K,
        const float* __restrict__ V,
        float* __restrict__ ws, float* __restrict__ gramP,
        float* __restrict__ ms1, float* __restrict__ ms2,
        float* __restrict__ vh) {
    const int ic = blockIdx.x;            // 0..7
    const int bh = blockIdx.y;            // 0..23
    const int which = blockIdx.z;         // 0=Q, 1=K, 2=Vh
    const int b = bh / HH, h = bh - b * HH;
    const int t = threadIdx.x;

    if (which == 2) {                     // Vh copy: 128 rows x 128 dh
        const float* srcv = V + (size_t)b * LL * DD + h * DHH;
        float* dstv = vh + ((size_t)bh * LL + (size_t)ic * 128) * DHH;
#pragma unroll
        for (int p = 0; p < 16; p++) {
            const int idx = p * 256 + t;          // 0..4095
            const int row = idx >> 5, d4 = idx & 31;
            f32x4 v = *(const f32x4*)(srcv + (size_t)(ic * 128 + row) * DD + d4 * 4);
            __builtin_nontemporal_store(v, (f32x4*)(dstv + (size_t)row * DHH + d4 * 4));
        }
        return;
    }

    const float* src = (which ? K : Q) + (size_t)b * LL * DD + h * DHH;
    float* sqout = ws + (which ? OFF_K2 : OFF_Q2) + bh * 1024 + ic * 128;

    const int lane = t & 63, wv = t >> 6;
    const int lm = lane & 15, quad = lane >> 4;

    __shared__ float tileT[128][129];     // [d][i] truncated fp32
    __shared__ float q2loc[128];

    // ---- stage + per-row sq-norm
    const int ig = t >> 5;                 // 0..7 (row subgroup)
    const int d0 = (t & 31) * 4;
#pragma unroll 4
    for (int p = 0; p < 16; p++) {
        const int i_loc = p * 8 + ig;
        float4 v = *(const float4*)(src + (size_t)(ic * 128 + i_loc) * DD + d0);
        tileT[d0 + 0][i_loc] = __uint_as_float(__float_as_uint(v.x) & 0xffff0000u);
        tileT[d0 + 1][i_loc] = __uint_as_float(__float_as_uint(v.y) & 0xffff0000u);
        tileT[d0 + 2][i_loc] = __uint_as_float(__float_as_uint(v.z) & 0xffff0000u);
        tileT[d0 + 3][i_loc] = __uint_as_float(__float_as_uint(v.w) & 0xffff0000u);
        float s = v.x * v.x + v.y * v.y + v.z * v.z + v.w * v.w;
#pragma unroll
        for (int off = 1; off < 32; off <<= 1) s += __shfl_xor(s, off);
        if ((t & 31) == 0) { q2loc[i_loc] = s; sqout[i_loc] = s; }
    }
    __syncthreads();

    // ---- per-d sums over this chunk
    if (t < 128) {
        float s1 = 0.f, s2 = 0.f;
#pragma unroll 8
        for (int i = 0; i < 128; i++) {
            float v = tileT[t][i];
            s1 += v;
            s2 += v * q2loc[i];
        }
        const size_t mo = ((size_t)(which * 24 + bh) * 8 + ic) * 128 + t;
        ms1[mo] = s1;
        ms2[mo] = s2;
    }

    // ---- Gram tile partials: pairs pi with pi%4==wv (9 per wave)
    const size_t gbase = ((size_t)(which * 24 + bh) * 8 + ic) * 9216;
    int pi = 0;
    for (int dt = 0; dt < 8; dt++) {
        for (int et = dt; et < 8; et++, pi++) {
            if ((pi & 3) != wv) continue;
            f32x4 acc = (f32x4)(0.0f);
#pragma unroll
            for (int kk = 0; kk < 4; kk++) {
                const int i0 = kk * 32 + quad * 8;
                const float* pa = &tileT[dt * 16 + lm][i0];
                const float* pb = &tileT[et * 16 + lm][i0];
                short8 af, bf;
#pragma unroll
                for (int e = 0; e < 8; e++) {
                    af[e] = (short)(__float_as_uint(pa[e]) >> 16);
                    bf[e] = (short)(__float_as_uint(pb[e]) >> 16);
                }
                acc = __builtin_amdgcn_mfma_f32_16x16x32_bf16(af, bf, acc, 0, 0, 0);
            }
            if (dt != et && which == 0) {
                acc[0] *= 2.f; acc[1] *= 2.f; acc[2] *= 2.f; acc[3] *= 2.f;
            }
            *(f32x4*)&gramP[gbase + (size_t)pi * 256 + lane * 4] = acc;
        }
    }
}

// ---- assemble analytic BN1 moments per bh (1024 thr: 16 waves hide L3 lat):
// sumS  = 2*dA - 1024*(Sq2+Sk2)
// sumS2 = 4*GG + 1024*(Sq2sq+Sk2sq) + 2*Sq2*Sk2 - 4*(dBq+dBk)
__global__ __launch_bounds__(1024) void k_stats3(
        const float* __restrict__ ms1, const float* __restrict__ ms2,
        const float* __restrict__ gramP,
        const float* __restrict__ q2, const float* __restrict__ k2,
        float* __restrict__ statsP) {
    const int bh = blockIdx.x;
    const int t = threadIdx.x, lane = t & 63, w = t >> 6;   // w 0..15
    __shared__ float sQ[128], sK[128], sQq2[128], sKk2[128];
    __shared__ float sred[16][4];
    __shared__ float gred[16];

    if (t < 256) {   // per-d chunk reduce
        const int d = t & 127, which = t >> 7;
        const float* p1 = ms1 + (size_t)(which * 24 + bh) * 1024 + d;
        const float* p2 = ms2 + (size_t)(which * 24 + bh) * 1024 + d;
        float s1 = 0.f, s2 = 0.f;
#pragma unroll
        for (int ic = 0; ic < 8; ic++) { s1 += p1[ic * 128]; s2 += p2[ic * 128]; }
        if (which) { sK[d] = s1; sKk2[d] = s2; }
        else       { sQ[d] = s1; sQq2[d] = s2; }
    }
    if (t >= 512 && t < 768) {   // scalar sums of q2/k2 and squares (waves 8-11)
        const int tt = t - 512;
        f32x4 qv = *(const f32x4*)(q2 + bh * 1024 + tt * 4);
        f32x4 kv = *(const f32x4*)(k2 + bh * 1024 + tt * 4);
        float p0 = qv[0] + qv[1] + qv[2] + qv[3];
        float p1 = qv[0]*qv[0] + qv[1]*qv[1] + qv[2]*qv[2] + qv[3]*qv[3];
        float p2 = kv[0] + kv[1] + kv[2] + kv[3];
        float p3 = kv[0]*kv[0] + kv[1]*kv[1] + kv[2]*kv[2] + kv[3]*kv[3];
#pragma unroll
        for (int off = 1; off < 64; off <<= 1) {
            p0 += __shfl_xor(p0, off); p1 += __shfl_xor(p1, off);
            p2 += __shfl_xor(p2, off); p3 += __shfl_xor(p3, off);
        }
        if (lane == 0) { sred[w][0] = p0; sred[w][1] = p1; sred[w][2] = p2; sred[w][3] = p3; }
    }
    {   // GG: flat over 36*256=9216 elems, chunks reduced BEFORE the product
        const float* gq = gramP + (size_t)(0 * 24 + bh) * 8 * 9216;
        const float* gk = gramP + (size_t)(1 * 24 + bh) * 8 * 9216;
        float gg = 0.f;
#pragma unroll
        for (int it = 0; it < 9; it++) {
            const int f = it * 1024 + t;
            float a = 0.f, c = 0.f;
#pragma unroll
            for (int icc = 0; icc < 8; icc++) {
                a += gq[(size_t)icc * 9216 + f];
                c += gk[(size_t)icc * 9216 + f];
            }
            gg += a * c;
        }
#pragma unroll
        for (int off = 1; off < 64; off <<= 1) gg += __shfl_xor(gg, off);
        if (lane == 0) gred[w] = gg;
    }
    __syncthreads();
    if (t < 64) {
        float dA  = sQ[t] * sK[t] + sQ[t + 64] * sK[t + 64];
        float dBq = sQq2[t] * sK[t] + sQq2[t + 64] * sK[t + 64];
        float dBk = sQ[t] * sKk2[t] + sQ[t + 64] * sKk2[t + 64];
#pragma unroll
        for (int off = 1; off < 64; off <<= 1) {
            dA += __shfl_xor(dA, off); dBq += __shfl_xor(dBq, off); dBk += __shfl_xor(dBk, off);
        }
        if (t == 0) {
            float SQ2   = sred[8][0] + sred[9][0] + sred[10][0] + sred[11][0];
            float SQ2SQ = sred[8][1] + sred[9][1] + sred[10][1] + sred[11][1];
            float SK2   = sred[8][2] + sred[9][2] + sred[10][2] + sred[11][2];
            float SK2SQ = sred[8][3] + sred[9][3] + sred[10][3] + sred[11][3];
            float GG = 0.f;
#pragma unroll
            for (int i = 0; i < 16; i++) GG += gred[i];
            float sumS  = 2.f * dA - 1024.f * (SQ2 + SK2);
            float sumS2 = 4.f * GG + 1024.f * (SQ2SQ + SK2SQ) + 2.f * SQ2 * SK2 - 4.f * (dBq + dBk);
            statsP[bh * 2]     = sumS;
            statsP[bh * 2 + 1] = sumS2;
        }
    }
}

// --------------------------------------------- BN1 stats -> ac
__global__ void k_stats2(const float* __restrict__ statsP,
                         const float* __restrict__ g1, const float* __restrict__ b1,
                         float* __restrict__ ac) {
    const int t = threadIdx.x;
    if (t < HH) {
        float T1 = 0.f, T2 = 0.f;
#pragma unroll
        for (int b = 0; b < 4; b++) {
            T1 += statsP[(b * HH + t) * 2];
            T2 += statsP[(b * HH + t) * 2 + 1];
        }
        const float N = 4194304.f;                 // 4*1024*1024
        float m_ = T1 / N;
        float var = fmaxf(T2 / N - m_ * m_, 0.0f);
        float r = rsqrtf(var + EPS);
        float a = r * g1[t];
        ac[t] = a;
        ac[8 + t] = b1[t] - m_ * a;
    }
}

// ---- FUSED: persistent blocks (1/CU), 3 strips of 32 rows each.
// Per strip: recompute S via MFMA (verified lane math) with double-buffered
// K prefetch, BN+mask+exp2 into 32x1028 LDS, row softmax (per-rep rowsum
// slot), coalesced NT stores. Phase-B store drain of strip s overlaps
// phase A of strip s+1 (no kernel-end vmcnt serialization per strip).
__global__ __launch_bounds__(512, 1) void k_fused(
        const float* __restrict__ Q, const float* __restrict__ Km,
        const float* __restrict__ q2, const float* __restrict__ k2,
        const float* __restrict__ ac, const unsigned char* __restrict__ bx,
        float* __restrict__ co, float* __restrict__ wcolP) {
    const int g = blockIdx.x;             // 0..255
    const int t = threadIdx.x, lane = t & 63, w = t >> 6;   // 8 waves
    const int lm = lane & 15, quad = lane >> 4;
    const int jw = w * 128;               // wave's 128-col range

    __shared__ float e_lds[32][1028];     // padded: balanced LDS banks
    __shared__ float rowsum[3][32];       // one slot per rep (no reset races)
    if (t < 96) ((float*)rowsum)[t] = 0.f;
    __syncthreads();

#pragma unroll 1
    for (int rep = 0; rep < 3; rep++) {
        const int f = g * 3 + rep;        // 0..767
        const int bh = f >> 5, strip = f & 31;
        const int b = bh / HH, h = bh - b * HH;
        const int i0 = strip * 32;
        const float* Qb = Q + (size_t)b * LL * DD + h * DHH;
        const float* Kb = Km + (size_t)b * LL * DD + h * DHH;
        const float a1 = ac[h], c1 = ac[8 + h];
        const unsigned char* bxb = bx + b * LL;
        const float a1l = a1 * LOG2E;
        const float a2l = 2.0f * a1l;
        const float c1l = c1 * LOG2E;

        // Q fragments (B-operand): two row-sets i0+s*16+lm, k-chunks by quad
        short8 qf[2][4];
#pragma unroll
        for (int s = 0; s < 2; s++)
#pragma unroll
            for (int kk = 0; kk < 4; kk++)
                qf[s][kk] = ld_bf8(Qb + (size_t)(i0 + s * 16 + lm) * DD + kk * 32 + quad * 8);

        bool vi0, vi1;
        float cr0, cr1;
        {
            vi0 = (bxb[i0 + lm] == 0);
            vi1 = (bxb[i0 + 16 + lm] == 0);
            cr0 = c1l - a1l * q2[bh * 1024 + i0 + lm];
            cr1 = c1l - a1l * q2[bh * 1024 + i0 + 16 + lm];
        }

        // K raw double-buffer: preload jt=0
        float4 raw[2][8];
#pragma unroll
        for (int kk = 0; kk < 4; kk++) {
            const float* p = Kb + (size_t)(jw + lm) * DD + kk * 32 + quad * 8;
            raw[0][2 * kk]     = *(const float4*)(p);
            raw[0][2 * kk + 1] = *(const float4*)(p + 4);
        }

        float rsum0 = 0.f, rsum1 = 0.f;
#pragma unroll
        for (int jt = 0; jt < 8; jt++) {
            const int cur = jt & 1;
            if (jt < 7) {                 // prefetch next jt's K rows
                const int jb2 = jw + (jt + 1) * 16;
#pragma unroll
                for (int kk = 0; kk < 4; kk++) {
                    const float* p = Kb + (size_t)(jb2 + lm) * DD + kk * 32 + quad * 8;
                    raw[cur ^ 1][2 * kk]     = *(const float4*)(p);
                    raw[cur ^ 1][2 * kk + 1] = *(const float4*)(p + 4);
                }
            }
            short8 kf[4];
#pragma unroll
            for (int kk = 0; kk < 4; kk++)
                kf[kk] = pack_bf8(raw[cur][2 * kk], raw[cur][2 * kk + 1]);
            f32x4 acc0 = (f32x4)(0.0f), acc1 = (f32x4)(0.0f);
#pragma unroll
            for (int kk = 0; kk < 4; kk++) {
                acc0 = __builtin_amdgcn_mfma_f32_16x16x32_bf16(kf[kk], qf[0][kk], acc0, 0, 0, 0);
                acc1 = __builtin_amdgcn_mfma_f32_16x16x32_bf16(kf[kk], qf[1][kk], acc1, 0, 0, 0);
            }
            // acc[r]: j = jb + quad*4 + r, i = i0 + s*16 + lm
            const int jb = jw + jt * 16;
            const f32x4 k2v = *(const f32x4*)(k2 + bh * 1024 + jb + quad * 4);
            const uchar4 m4 = *(const uchar4*)(bxb + jb + quad * 4);
            const bool vj0 = (m4.x == 0), vj1 = (m4.y == 0), vj2 = (m4.z == 0), vj3 = (m4.w == 0);
            f32x4 kc;
            kc[0] = a1l * k2v[0]; kc[1] = a1l * k2v[1];
            kc[2] = a1l * k2v[2]; kc[3] = a1l * k2v[3];
            {
                f32x4 ev;
                ev[0] = (vi0 && vj0) ? exp2f(fminf(fmaf(a2l, acc0[0], cr0 - kc[0]), 86.56f)) : 1.0f;
                ev[1] = (vi0 && vj1) ? exp2f(fminf(fmaf(a2l, acc0[1], cr0 - kc[1]), 86.56f)) : 1.0f;
                ev[2] = (vi0 && vj2) ? exp2f(fminf(fmaf(a2l, acc0[2], cr0 - kc[2]), 86.56f)) : 1.0f;
                ev[3] = (vi0 && vj3) ? exp2f(fminf(fmaf(a2l, acc0[3], cr0 - kc[3]), 86.56f)) : 1.0f;
                *(f32x4*)&e_lds[lm][jb + quad * 4] = ev;
                rsum0 += (ev[0] + ev[1]) + (ev[2] + ev[3]);
            }
            {
                f32x4 ev;
                ev[0] = (vi1 && vj0) ? exp2f(fminf(fmaf(a2l, acc1[0], cr1 - kc[0]), 86.56f)) : 1.0f;
                ev[1] = (vi1 && vj1) ? exp2f(fminf(fmaf(a2l, acc1[1], cr1 - kc[1]), 86.56f)) : 1.0f;
                ev[2] = (vi1 && vj2) ? exp2f(fminf(fmaf(a2l, acc1[2], cr1 - kc[2]), 86.56f)) : 1.0f;
                ev[3] = (vi1 && vj3) ? exp2f(fminf(fmaf(a2l, acc1[3], cr1 - kc[3]), 86.56f)) : 1.0f;
                *(f32x4*)&e_lds[16 + lm][jb + quad * 4] = ev;
                rsum1 += (ev[0] + ev[1]) + (ev[2] + ev[3]);
            }
        }
        // row-sum: reduce over quads, then across waves via LDS atomics
        rsum0 += __shfl_xor(rsum0, 16);
        rsum0 += __shfl_xor(rsum0, 32);
        rsum1 += __shfl_xor(rsum1, 16);
        rsum1 += __shfl_xor(rsum1, 32);
        if (lane < 16) {
            atomicAdd(&rowsum[rep][lm], rsum0);
            atomicAdd(&rowsum[rep][16 + lm], rsum1);
        }
        __syncthreads();

        // phase B: coalesced scaled NT stores + half-strip col sums
        const int cg = t & 255, rh = t >> 8;
        float* cob = co + ((size_t)bh << 20) + (size_t)(i0 + rh * 16) * 1024 + cg * 4;
        float* wp = wcolP + ((size_t)((strip * 2 + rh) * 24 + bh)) * 1024 + cg * 4;
        float cs0 = 0.f, cs1 = 0.f, cs2 = 0.f, cs3 = 0.f;
#pragma unroll
        for (int rr = 0; rr < 16; rr++) {
            const int r = rh * 16 + rr;
            const float inv = 1.0f / rowsum[rep][r];
            f32x4 v = *(const f32x4*)&e_lds[r][cg * 4];
            v[0] *= inv; v[1] *= inv; v[2] *= inv; v[3] *= inv;
            __builtin_nontemporal_store(v, (f32x4*)(cob + (size_t)rr * 1024));
            cs0 += v[0]; cs1 += v[1]; cs2 += v[2]; cs3 += v[3];
        }
        f32x4 wv; wv[0] = cs0; wv[1] = cs1; wv[2] = cs2; wv[3] = cs3;
        *(f32x4*)wp = wv;
        __syncthreads();   // e_lds free for next rep (stores already issued)
    }
}

// ---- reduce col-sum half-strip partials -> wcol; fused BN2 block partials
__global__ void k_wcol_reduce(const float* __restrict__ wcolP,
                              float* __restrict__ wcol, float* __restrict__ ws2) {
    const int t = threadIdx.x;
    int g = blockIdx.x * 256 + t;                    // 24576
    float s = 0.f;
#pragma unroll 8
    for (int strip = 0; strip < 64; strip++)
        s += wcolP[(size_t)strip * 24576 + g];
    wcol[g] = s;
    float a = s, b = s * s;
#pragma unroll
    for (int off = 1; off < 64; off <<= 1) { a += __shfl_xor(a, off); b += __shfl_xor(b, off); }
    __shared__ float sc[4][2];
    if ((t & 63) == 0) { sc[t >> 6][0] = a; sc[t >> 6][1] = b; }
    __syncthreads();
    if (t == 0) {
        ws2[blockIdx.x * 2]     = sc[0][0] + sc[1][0] + sc[2][0] + sc[3][0];
        ws2[blockIdx.x * 2 + 1] = sc[0][1] + sc[1][1] + sc[2][1] + sc[3][1];
    }
}

// ------- tail: BN2 (from block partials) + gate + per-batch softmax
__global__ __launch_bounds__(1024) void k_tail(
        const float* __restrict__ wcol, const float* __restrict__ ws2,
        const unsigned char* __restrict__ bx,
        const float* __restrict__ g2, const float* __restrict__ b2,
        const float* __restrict__ Wp, const float* __restrict__ bp,
        float* __restrict__ wout) {
    const int t = threadIdx.x, lane = t & 63, wv = t >> 6;
    __shared__ float abuf[12];       // a2s[0..5], c2s[6..11]
    __shared__ float xb[4096];
    __shared__ float wred[16][2];

    if (t < HH) {
        float s = 0.f, s2 = 0.f;
        for (int b = 0; b < 4; b++) {
            int bh = b * HH + t;
#pragma unroll
            for (int sub = 0; sub < 4; sub++) {
                int blk = bh * 4 + sub;
                s += ws2[blk * 2];
                s2 += ws2[blk * 2 + 1];
            }
        }
        float m = s / 4096.f;
        float var = fmaxf(s2 / 4096.f - m * m, 0.0f);
        float r = rsqrtf(var + EPS);
        float a = r * g2[t];
        abuf[t] = a;
        abuf[6 + t] = b2[t] - m * a;
    }
    __syncthreads();

    const float bp0 = bp[0], bp1 = bp[1];
#pragma unroll
    for (int p = 0; p < 4; p++) {
        int idx = t + p * 1024;
        int b = idx >> 10, l = idx & 1023;
        float z0 = bp0, z1 = bp1;
#pragma unroll
        for (int h = 0; h < HH; h++) {
            float wn = abuf[h] * wcol[(size_t)(b * HH + h) * 1024 + l] + abuf[6 + h];
            z0 += wn * Wp[h];
            z1 += wn * Wp[HH + h];
        }
        float pc = 1.0f / (1.0f + __expf(z1 - z0));
        xb[idx] = bx[b * LL + l] ? -INFINITY : pc;
    }
    __syncthreads();

    const int bb = t >> 8, tb = t & 255;
    float4 xv = *(const float4*)&xb[bb * 1024 + tb * 4];
    float mx = fmaxf(fmaxf(xv.x, xv.y), fmaxf(xv.z, xv.w));
#pragma unroll
    for (int off = 1; off < 64; off <<= 1) mx = fmaxf(mx, __shfl_xor(mx, off));
    if (lane == 0) wred[wv][0] = mx;
    __syncthreads();
    mx = fmaxf(fmaxf(wred[bb * 4][0], wred[bb * 4 + 1][0]),
               fmaxf(wred[bb * 4 + 2][0], wred[bb * 4 + 3][0]));
    float e0 = __expf(xv.x - mx), e1 = __expf(xv.y - mx);
    float e2 = __expf(xv.z - mx), e3 = __expf(xv.w - mx);
    float ss = e0 + e1 + e2 + e3;
#pragma unroll
    for (int off = 1; off < 64; off <<= 1) ss += __shfl_xor(ss, off);
    if (lane == 0) wred[wv][1] = ss;
    __syncthreads();
    float sum = wred[bb * 4][1] + wred[bb * 4 + 1][1] + wred[bb * 4 + 2][1] + wred[bb * 4 + 3][1];
    float4 o;
    o.x = e0 / sum; o.y = e1 / sum; o.z = e2 / sum; o.w = e3 / sum;
    *(float4*)&wout[bb * 1024 + tb * 4] = o;
}

extern "C" void kernel_launch(void* const* d_in, const int* in_sizes, int n_in,
                              void* d_out, int out_size, void* d_ws, size_t ws_size,
                              hipStream_t stream) {
    const float* Q  = (const float*)d_in[0];
    const float* K  = (const float*)d_in[1];
    const float* V  = (const float*)d_in[2];
    // d_in[3] = pad_mask — derivable from bx_packed, unused
    const unsigned char* bx = (const unsigned char*)d_in[4];
    const float* g1 = (const float*)d_in[5];
    const float* b1 = (const float*)d_in[6];
    const float* g2 = (const float*)d_in[7];
    const float* b2 = (const float*)d_in[8];
    const float* Wp = (const float*)d_in[9];
    const float* bp = (const float*)d_in[10];

    float* out  = (float*)d_out;
    float* co   = out;                        // (B,H,L,L)
    float* wout = out + CO_ELEMS;             // (B,L,1)
    float* vh   = out + CO_ELEMS + W_ELEMS;   // (B,H,L,DH)

    float* ws = (float*)d_ws;                 // ~21.2 MB
    float* q2     = ws + OFF_Q2;
    float* k2     = ws + OFF_K2;
    float* wcol   = ws + OFF_WC;
    float* statsP = ws + OFF_SP;
    float* ac     = ws + OFF_AC;
    float* ws2    = ws + OFF_SS;
    float* wcolP  = ws + OFF_WP;
    float* gramP  = ws + OFF_GP;
    float* ms1    = ws + OFF_MS1;
    float* ms2    = ws + OFF_MS2;

    k_gram<<<dim3(8, 24, 3), 256, 0, stream>>>(Q, K, V, ws, gramP, ms1, ms2, vh);
    k_stats3<<<24, 1024, 0, stream>>>(ms1, ms2, gramP, q2, k2, statsP);
    k_stats2<<<1, 64, 0, stream>>>(statsP, g1, b1, ac);
    k_fused<<<256, 512, 0, stream>>>(Q, K, q2, k2, ac, bx, co, wcolP);
    k_wcol_reduce<<<96, 256, 0, stream>>>(wcolP, wcol, ws2);
    k_tail<<<1, 1024, 0, stream>>>(wcol, ws2, bx, g2, b2, Wp, bp, wout);
}